// Round 3
// baseline (2477.544 us; speedup 1.0000x reference)
//
#include <hip/hip_runtime.h>
#include <hip/hip_bf16.h>
#include <cstdint>

typedef unsigned short u16;
typedef unsigned int u32;
typedef __attribute__((ext_vector_type(8))) short short8;
typedef __attribute__((ext_vector_type(4))) float f32x4;

#define NB 8
#define NS 2048
#define ND 512
#define NM (NB * NS)            // 16384 rows
static constexpr size_t BSDn = (size_t)NM * ND;   // 8388608 elems
#define KSCALE 0.044194173824159216f              // 1/sqrt(512)

__device__ __forceinline__ u16 f2bf(float f) {
    u32 i = __builtin_bit_cast(u32, f);
    u32 r = i + 0x7FFFu + ((i >> 16) & 1u);   // round-to-nearest-even
    return (u16)(r >> 16);
}
__device__ __forceinline__ float bf2f(u16 h) {
    return __builtin_bit_cast(float, (u32)h << 16);
}

// ---------------- split-precision weight build for the 6 projections:
// WcorrT [3072][1024] bf16: row n (proj p=n>>9, col d=n&511):
//   k in [0,512):   WL[k][d] = bf16(W_p[k][d] - fl32(bf16(W_p[k][d])))
//   k in [512,1024): WH[k-512][d] = bf16(W_p[k][d])
__global__ __launch_bounds__(256) void wcorr_kernel(
        const float* __restrict__ W0, const float* __restrict__ W1,
        const float* __restrict__ W2, const float* __restrict__ W3,
        const float* __restrict__ W4, const float* __restrict__ W5,
        u16* __restrict__ WT) {
    int idx = blockIdx.x * 256 + threadIdx.x;   // 3072*1024
    int n = idx >> 10, k = idx & 1023;
    int p = n >> 9, d = n & 511;
    const float* Wp;
    switch (p) {
        case 0: Wp = W0; break;
        case 1: Wp = W1; break;
        case 2: Wp = W2; break;
        case 3: Wp = W3; break;
        case 4: Wp = W4; break;
        default: Wp = W5; break;
    }
    u16 o;
    if (k >= 512) {
        o = f2bf(Wp[(size_t)(k - 512) * 512 + d]);
    } else {
        float w = Wp[(size_t)k * 512 + d];
        o = f2bf(w - bf2f(f2bf(w)));
    }
    WT[idx] = o;
}

// ---------------- plain weight convert + transpose: WT[n*K + k] = bf16(W[k*N + n])
__global__ __launch_bounds__(256) void wconv_kernel(const float* __restrict__ W,
        u16* __restrict__ WT, int lk, int N, int total) {
    int idx = blockIdx.x * 256 + threadIdx.x;
    if (idx >= total) return;
    int n = idx >> lk;
    int k = idx & ((1 << lk) - 1);
    WT[idx] = f2bf(W[(size_t)k * N + n]);
}

// ---------------- concat 6 projection biases into [3072]
__global__ __launch_bounds__(256) void bias_concat_kernel(
        const float* b0, const float* b1, const float* b2,
        const float* b3, const float* b4, const float* b5,
        float* __restrict__ ball) {
    int idx = blockIdx.x * 256 + threadIdx.x;
    if (idx >= 3072) return;
    int p = idx >> 9, d = idx & 511;
    float v;
    switch (p) {
        case 0: v = b0[d]; break;
        case 1: v = b1[d]; break;
        case 2: v = b2[d]; break;
        case 3: v = b3[d]; break;
        case 4: v = b4[d]; break;
        default: v = b5[d]; break;
    }
    ball[idx] = v;
}

// ---------------- LN1: x [16384,512] f32 -> Acorr [16384][1024] = [nH | nL]
__global__ __launch_bounds__(256) void ln1_kernel(const float* __restrict__ x,
        const float* __restrict__ g, const float* __restrict__ bb,
        u16* __restrict__ nout) {
    int wave = threadIdx.x >> 6, lane = threadIdx.x & 63;
    size_t row = (size_t)blockIdx.x * 4 + wave;
    const float* xr = x + row * ND + lane * 8;
    float4 a0 = *(const float4*)xr;
    float4 a1 = *(const float4*)(xr + 4);
    float xs[8] = {a0.x, a0.y, a0.z, a0.w, a1.x, a1.y, a1.z, a1.w};
    float s = 0.f;
#pragma unroll
    for (int u = 0; u < 8; ++u) s += xs[u];
#pragma unroll
    for (int off = 32; off; off >>= 1) s += __shfl_xor(s, off);
    float mu = s * (1.0f / ND);
    float ss = 0.f;
#pragma unroll
    for (int u = 0; u < 8; ++u) { xs[u] -= mu; ss += xs[u] * xs[u]; }
#pragma unroll
    for (int off = 32; off; off >>= 1) ss += __shfl_xor(ss, off);
    float rs = rsqrtf(ss * (1.0f / ND) + 1e-5f);
    const float* gp = g + lane * 8;
    const float* bp = bb + lane * 8;
    float4 g0 = *(const float4*)gp, g1 = *(const float4*)(gp + 4);
    float4 c0 = *(const float4*)bp, c1 = *(const float4*)(bp + 4);
    float gg[8] = {g0.x, g0.y, g0.z, g0.w, g1.x, g1.y, g1.z, g1.w};
    float cc[8] = {c0.x, c0.y, c0.z, c0.w, c1.x, c1.y, c1.z, c1.w};
    u32 owh[4], owl[4];
#pragma unroll
    for (int u = 0; u < 4; ++u) {
        float y0 = xs[2 * u] * rs * gg[2 * u] + cc[2 * u];
        float y1 = xs[2 * u + 1] * rs * gg[2 * u + 1] + cc[2 * u + 1];
        u16 h0 = f2bf(y0), h1 = f2bf(y1);
        u16 l0 = f2bf(y0 - bf2f(h0)), l1 = f2bf(y1 - bf2f(h1));
        owh[u] = (u32)h0 | ((u32)h1 << 16);
        owl[u] = (u32)l0 | ((u32)l1 << 16);
    }
    u16* rb = nout + row * 1024;
    *(uint4*)(rb + lane * 8) = make_uint4(owh[0], owh[1], owh[2], owh[3]);
    *(uint4*)(rb + 512 + lane * 8) = make_uint4(owl[0], owl[1], owl[2], owl[3]);
}

// ---------------- residual add + LN2: out = x + h (f32 -> d_out), fin = LN2(out) bf16
__global__ __launch_bounds__(256) void resid_ln2_kernel(const float* __restrict__ x,
        const float* __restrict__ h, const float* __restrict__ g,
        const float* __restrict__ bb, float* __restrict__ outb,
        u16* __restrict__ fin) {
    int wave = threadIdx.x >> 6, lane = threadIdx.x & 63;
    size_t row = (size_t)blockIdx.x * 4 + wave;
    const float* xr = x + row * ND + lane * 8;
    const float* hr = h + row * ND + lane * 8;
    float4 a0 = *(const float4*)xr;
    float4 a1 = *(const float4*)(xr + 4);
    float4 h0 = *(const float4*)hr;
    float4 h1 = *(const float4*)(hr + 4);
    float xs[8] = {a0.x + h0.x, a0.y + h0.y, a0.z + h0.z, a0.w + h0.w,
                   a1.x + h1.x, a1.y + h1.y, a1.z + h1.z, a1.w + h1.w};
    float* orow = outb + row * ND + lane * 8;
    *(float4*)orow = make_float4(xs[0], xs[1], xs[2], xs[3]);
    *(float4*)(orow + 4) = make_float4(xs[4], xs[5], xs[6], xs[7]);
    float s = 0.f;
#pragma unroll
    for (int u = 0; u < 8; ++u) s += xs[u];
#pragma unroll
    for (int off = 32; off; off >>= 1) s += __shfl_xor(s, off);
    float mu = s * (1.0f / ND);
    float ss = 0.f;
#pragma unroll
    for (int u = 0; u < 8; ++u) { xs[u] -= mu; ss += xs[u] * xs[u]; }
#pragma unroll
    for (int off = 32; off; off >>= 1) ss += __shfl_xor(ss, off);
    float rs = rsqrtf(ss * (1.0f / ND) + 1e-5f);
    const float* gp = g + lane * 8;
    const float* bp = bb + lane * 8;
    float4 g0 = *(const float4*)gp, g1 = *(const float4*)(gp + 4);
    float4 c0 = *(const float4*)bp, c1 = *(const float4*)(bp + 4);
    float gg[8] = {g0.x, g0.y, g0.z, g0.w, g1.x, g1.y, g1.z, g1.w};
    float cc[8] = {c0.x, c0.y, c0.z, c0.w, c1.x, c1.y, c1.z, c1.w};
    u32 ow[4];
#pragma unroll
    for (int u = 0; u < 4; ++u) {
        float y0 = xs[2 * u] * rs * gg[2 * u] + cc[2 * u];
        float y1 = xs[2 * u + 1] * rs * gg[2 * u + 1] + cc[2 * u + 1];
        ow[u] = (u32)f2bf(y0) | ((u32)f2bf(y1) << 16);
    }
    *(uint4*)(fin + row * ND + lane * 8) = make_uint4(ow[0], ow[1], ow[2], ow[3]);
}

// ---------------- mLSTM recurrence. One wave per (b, i) row.
// C[b,i,j] in registers: lane holds j = lane*8 .. lane*8+7.
// P layout [6][NM][ND] f32: q, k(raw), v, it, ft, o(raw logit)
// k-scale (1/sqrt(D)) folded into iv; sigmoid applied here.
__global__ __launch_bounds__(256) void recur_kernel(const float* __restrict__ P,
        float* __restrict__ H) {
    int wave = threadIdx.x >> 6, lane = threadIdx.x & 63;
    int gb = blockIdx.x;                  // 0..1023
    int b = gb >> 7;                      // 8 batches * 128 blocks
    int i = ((gb & 127) << 2) + wave;     // 0..511
    const float* Qp = P;
    const float* Kp = P + BSDn;
    const float* Vp = P + 2 * BSDn;
    const float* Ip = P + 3 * BSDn;
    const float* Fp = P + 4 * BSDn;
    const float* Op = P + 5 * BSDn;
    float c[8];
#pragma unroll
    for (int u = 0; u < 8; ++u) c[u] = 0.f;
    float m = 0.f;
    size_t base = (size_t)b * NS * ND;
    for (int t = 0; t < NS; ++t) {
        size_t roff = base + (size_t)t * ND;
        const float* kr = Kp + roff + lane * 8;
        const float* qr = Qp + roff + lane * 8;
        float4 k0 = *(const float4*)kr;
        float4 k1 = *(const float4*)(kr + 4);
        float4 q0 = *(const float4*)qr;
        float4 q1 = *(const float4*)(qr + 4);
        float itv = Ip[roff + i];
        float ftv = Fp[roff + i];
        float vv  = Vp[roff + i];
        float olg = Op[roff + i];
        float ov = 1.0f / (1.0f + __expf(-olg));
        float mn = fmaxf(ftv + m, itv);
        float ig = __expf(itv - mn);
        float fg = __expf(ftv + m - mn);
        float iv = ig * vv * KSCALE;      // fold k-scale into iv
        float kk[8] = {k0.x, k0.y, k0.z, k0.w, k1.x, k1.y, k1.z, k1.w};
        float qq[8] = {q0.x, q0.y, q0.z, q0.w, q1.x, q1.y, q1.z, q1.w};
        float acc = 0.f;
#pragma unroll
        for (int u = 0; u < 8; ++u) {
            c[u] = fg * c[u] + iv * kk[u];
            acc += c[u] * qq[u];
        }
#pragma unroll
        for (int off = 32; off; off >>= 1) acc += __shfl_xor(acc, off);
        if (lane == 0) H[roff + i] = ov * acc;
        m = mn;
    }
}

// ---------------- bf16 MFMA GEMM: C[M,N] = A[M,K] @ BT[N,K]^T, fused epilogues
// MODE 0: proj main  -> P[p][row][d] = acc + bias (f32, raw)
// MODE 3: proj corr  -> P[p][row][d] += acc        (split-bf16 correction)
// MODE 1: ffn1       -> gelu(acc+b1) bf16 [M,N]
// MODE 2: ffn2       -> acc + b2 + resid -> f32 [M,N]
#define LP 40   // LDS row pitch in bf16 elems (32 + 8 pad)
template <int MODE>
__global__ __launch_bounds__(256) void gemm_kernel(
        const u16* __restrict__ A, const u16* __restrict__ BT,
        int M, int N, int K, int lda, int ldb,
        const float* __restrict__ bias,
        float* __restrict__ outf, u16* __restrict__ outh,
        const float* __restrict__ resid) {
    __shared__ u16 As[128 * LP];
    __shared__ u16 Bs[128 * LP];
    int tid = threadIdx.x;
    int wave = tid >> 6, lane = tid & 63;
    int wm = wave >> 1, wn = wave & 1;
    int m0 = blockIdx.y * 128;
    int n0 = blockIdx.x * 128;

    f32x4 acc[4][4];
#pragma unroll
    for (int fi = 0; fi < 4; ++fi)
#pragma unroll
        for (int fj = 0; fj < 4; ++fj)
            acc[fi][fj] = (f32x4){0.f, 0.f, 0.f, 0.f};

    int sr = tid >> 1;            // staging row 0..127
    int sh = (tid & 1) << 4;      // elem offset 0 or 16
    const u16* Ag = A + (size_t)(m0 + sr) * lda + sh;
    const u16* Bg = BT + (size_t)(n0 + sr) * ldb + sh;
    u16* Asw = &As[sr * LP + sh];
    u16* Bsw = &Bs[sr * LP + sh];

    int fr = lane & 15, kb = lane >> 4;
    const u16* Ard = &As[(wm * 64 + fr) * LP + kb * 8];
    const u16* Brd = &Bs[(wn * 64 + fr) * LP + kb * 8];

    for (int k0 = 0; k0 < K; k0 += 32) {
        uint4 av0 = *(const uint4*)(Ag + k0);
        uint4 av1 = *(const uint4*)(Ag + k0 + 8);
        uint4 bv0 = *(const uint4*)(Bg + k0);
        uint4 bv1 = *(const uint4*)(Bg + k0 + 8);
        __syncthreads();
        *(uint4*)Asw = av0;
        *(uint4*)(Asw + 8) = av1;
        *(uint4*)Bsw = bv0;
        *(uint4*)(Bsw + 8) = bv1;
        __syncthreads();
        short8 fa[4], fb[4];
#pragma unroll
        for (int f = 0; f < 4; ++f) {
            fa[f] = *(const short8*)(Ard + f * 16 * LP);
            fb[f] = *(const short8*)(Brd + f * 16 * LP);
        }
#pragma unroll
        for (int fi = 0; fi < 4; ++fi)
#pragma unroll
            for (int fj = 0; fj < 4; ++fj)
                acc[fi][fj] = __builtin_amdgcn_mfma_f32_16x16x32_bf16(
                        fa[fi], fb[fj], acc[fi][fj], 0, 0, 0);
    }

    int rbase = (lane >> 4) * 4;
    int cbase = n0 + wn * 64 + (lane & 15);
#pragma unroll
    for (int fi = 0; fi < 4; ++fi) {
#pragma unroll
        for (int fj = 0; fj < 4; ++fj) {
            int col = cbase + fj * 16;
#pragma unroll
            for (int r = 0; r < 4; ++r) {
                int row = m0 + wm * 64 + fi * 16 + rbase + r;
                float v = acc[fi][fj][r];
                if (MODE == 0) {
                    size_t idx = (size_t)(col >> 9) * BSDn + (size_t)row * ND + (col & 511);
                    outf[idx] = v + bias[col];
                } else if (MODE == 3) {
                    size_t idx = (size_t)(col >> 9) * BSDn + (size_t)row * ND + (col & 511);
                    outf[idx] += v;
                } else if (MODE == 1) {
                    float val = v + bias[col];
                    val = 0.5f * val * (1.0f + erff(val * 0.70710678118654752f));
                    outh[(size_t)row * N + col] = f2bf(val);
                } else {
                    float val = v + bias[col] + resid[(size_t)row * ND + col];
                    outf[(size_t)row * ND + col] = val;
                }
            }
        }
    }
}

extern "C" void kernel_launch(void* const* d_in, const int* in_sizes, int n_in,
                              void* d_out, int out_size, void* d_ws, size_t ws_size,
                              hipStream_t stream) {
    const float* x    = (const float*)d_in[0];
    const float* ln1g = (const float*)d_in[1];
    const float* ln1b = (const float*)d_in[2];
    const float* ln2g = (const float*)d_in[3];
    const float* ln2b = (const float*)d_in[4];
    const float* Wq = (const float*)d_in[5];
    const float* bq = (const float*)d_in[6];
    const float* Wk = (const float*)d_in[7];
    const float* bk = (const float*)d_in[8];
    const float* Wv = (const float*)d_in[9];
    const float* bv = (const float*)d_in[10];
    const float* Wi = (const float*)d_in[11];
    const float* bi = (const float*)d_in[12];
    const float* Wf = (const float*)d_in[13];
    const float* bfp = (const float*)d_in[14];
    const float* Wo = (const float*)d_in[15];
    const float* bo = (const float*)d_in[16];
    const float* W1 = (const float*)d_in[17];
    const float* b1 = (const float*)d_in[18];
    const float* W2 = (const float*)d_in[19];
    const float* b2 = (const float*)d_in[20];
    float* out = (float*)d_out;

    // ---- workspace layout ----
    char* ws = (char*)d_ws;
    size_t off = 0;
    u16* WcorrT = (u16*)(ws + off); off += (size_t)3072 * 1024 * 2;  // 6 MB [WL;WH]
    u16* W1T    = (u16*)(ws + off); off += (size_t)2048 * 512 * 2;   // 2 MB
    u16* W2T    = (u16*)(ws + off); off += (size_t)512 * 2048 * 2;   // 2 MB
    float* ball = (float*)(ws + off); off += 3072 * 4;               // 12 KB
    off = (off + 255) & ~(size_t)255;
    char* U = ws + off;
    // P: [6][NM][ND] f32 = 192 MB (q,k,v,it,ft,o)
    float* Pf = (float*)U;
    // 32 MB slot at U+192MB: Acorr [16384][1024] bf16, later aliased by Hbuf f32
    u16*   Acorr = (u16*)(U + (size_t)192 * 1024 * 1024);
    float* Hbuf  = (float*)(U + (size_t)192 * 1024 * 1024);
    // aliases of dead P (steps 5-7):
    u16* ffnin = (u16*)U;                       // 16 MB
    u16* Gbuf  = (u16*)(U + BSDn * 2);          // 64 MB
    size_t needed = (size_t)(U - ws) + (size_t)224 * 1024 * 1024;
    if (ws_size < needed) return;   // fails with absmax == max|ref| -> ws diagnosis

    // 1. weights
    wcorr_kernel<<<12288, 256, 0, stream>>>(Wq, Wk, Wv, Wi, Wf, Wo, WcorrT);
    wconv_kernel<<<4096, 256, 0, stream>>>(W1, W1T, 9, 2048, 2048 * 512);
    wconv_kernel<<<4096, 256, 0, stream>>>(W2, W2T, 11, 512, 512 * 2048);
    bias_concat_kernel<<<12, 256, 0, stream>>>(bq, bk, bv, bi, bfp, bo, ball);

    // 2. LN1 -> [nH | nL]
    ln1_kernel<<<NM / 4, 256, 0, stream>>>(x, ln1g, ln1b, Acorr);

    // 3a. main proj GEMM: nH @ WH  (B rows offset +512 into [WL;WH])
    gemm_kernel<0><<<dim3(3072 / 128, NM / 128), 256, 0, stream>>>(
            Acorr, WcorrT + 512, NM, 3072, 512, 1024, 1024, ball, Pf, nullptr, nullptr);
    // 3b. correction GEMM: [nH|nL] @ [WL;WH]  (K=1024), adds into Pf
    gemm_kernel<3><<<dim3(3072 / 128, NM / 128), 256, 0, stream>>>(
            Acorr, WcorrT, NM, 3072, 1024, 1024, 1024, nullptr, Pf, nullptr, nullptr);

    // 4. recurrence
    recur_kernel<<<1024, 256, 0, stream>>>(Pf, Hbuf);

    // 5. residual + LN2 (out = x + h -> d_out; LN2 -> ffnin)
    resid_ln2_kernel<<<NM / 4, 256, 0, stream>>>(x, Hbuf, ln2g, ln2b, out, ffnin);

    // 6. FFN1: [16384,512] @ [512,2048], gelu
    gemm_kernel<1><<<dim3(2048 / 128, NM / 128), 256, 0, stream>>>(
            ffnin, W1T, NM, 2048, 512, 512, 512, b1, nullptr, Gbuf, nullptr);

    // 7. FFN2: [16384,2048] @ [2048,512], + b2 + residual(d_out) -> d_out
    gemm_kernel<2><<<dim3(512 / 128, NM / 128), 256, 0, stream>>>(
            Gbuf, W2T, NM, 512, 2048, 2048, 2048, b2, out, nullptr, out);

    (void)in_sizes; (void)n_in; (void)out_size; (void)ws_size;
}

// Round 4
// 2020.984 us; speedup vs baseline: 1.2259x; 1.2259x over previous
//
#include <hip/hip_runtime.h>
#include <hip/hip_bf16.h>
#include <cstdint>

typedef unsigned short u16;
typedef unsigned int u32;
typedef __attribute__((ext_vector_type(8))) short short8;
typedef __attribute__((ext_vector_type(4))) float f32x4;

#define NB 8
#define NS 2048
#define ND 512
#define NM (NB * NS)            // 16384 rows
static constexpr size_t BSDn = (size_t)NM * ND;   // 8388608 elems
#define KSCALE 0.044194173824159216f              // 1/sqrt(512)

// Pf slot byte offsets: q,k,it,ft f32; v,o bf16 (transposed [b,d,t] for it,ft,v,o)
#define OFF_Q  ((size_t)0)
#define OFF_K  (BSDn * 4)
#define OFF_IT (BSDn * 8)
#define OFF_FT (BSDn * 12)
#define OFF_V  (BSDn * 16)
#define OFF_O  (BSDn * 18)
#define PF_BYTES (BSDn * 20)    // 160 MB

__device__ __forceinline__ u16 f2bf(float f) {
    u32 i = __builtin_bit_cast(u32, f);
    u32 r = i + 0x7FFFu + ((i >> 16) & 1u);   // round-to-nearest-even
    return (u16)(r >> 16);
}
__device__ __forceinline__ float bf2f(u16 h) {
    return __builtin_bit_cast(float, (u32)h << 16);
}
__device__ __forceinline__ float bflo(u32 w) {
    return __builtin_bit_cast(float, w << 16);
}
__device__ __forceinline__ float bfhi(u32 w) {
    return __builtin_bit_cast(float, w & 0xffff0000u);
}

// ---------------- split-precision weight build, [3072][1536] = [WH | WH | WL]
__global__ __launch_bounds__(256) void wcorr_kernel(
        const float* __restrict__ W0, const float* __restrict__ W1,
        const float* __restrict__ W2, const float* __restrict__ W3,
        const float* __restrict__ W4, const float* __restrict__ W5,
        u16* __restrict__ WT) {
    int idx = blockIdx.x * 256 + threadIdx.x;   // 3072*1536
    int n = idx / 1536, k = idx - n * 1536;
    int p = n >> 9, d = n & 511;
    const float* Wp;
    switch (p) {
        case 0: Wp = W0; break;
        case 1: Wp = W1; break;
        case 2: Wp = W2; break;
        case 3: Wp = W3; break;
        case 4: Wp = W4; break;
        default: Wp = W5; break;
    }
    u16 o;
    if (k < 1024) {
        o = f2bf(Wp[(size_t)(k & 511) * 512 + d]);
    } else {
        float w = Wp[(size_t)(k - 1024) * 512 + d];
        o = f2bf(w - bf2f(f2bf(w)));
    }
    WT[idx] = o;
}

// ---------------- plain weight convert + transpose: WT[n*K + k] = bf16(W[k*N + n])
__global__ __launch_bounds__(256) void wconv_kernel(const float* __restrict__ W,
        u16* __restrict__ WT, int lk, int N, int total) {
    int idx = blockIdx.x * 256 + threadIdx.x;
    if (idx >= total) return;
    int n = idx >> lk;
    int k = idx & ((1 << lk) - 1);
    WT[idx] = f2bf(W[(size_t)k * N + n]);
}

// ---------------- concat 6 projection biases into [3072]
__global__ __launch_bounds__(256) void bias_concat_kernel(
        const float* b0, const float* b1, const float* b2,
        const float* b3, const float* b4, const float* b5,
        float* __restrict__ ball) {
    int idx = blockIdx.x * 256 + threadIdx.x;
    if (idx >= 3072) return;
    int p = idx >> 9, d = idx & 511;
    float v;
    switch (p) {
        case 0: v = b0[d]; break;
        case 1: v = b1[d]; break;
        case 2: v = b2[d]; break;
        case 3: v = b3[d]; break;
        case 4: v = b4[d]; break;
        default: v = b5[d]; break;
    }
    ball[idx] = v;
}

// ---------------- LN1: x [16384,512] f32 -> Acorr [16384][1024] = [nH | nL]
__global__ __launch_bounds__(256) void ln1_kernel(const float* __restrict__ x,
        const float* __restrict__ g, const float* __restrict__ bb,
        u16* __restrict__ nout) {
    int wave = threadIdx.x >> 6, lane = threadIdx.x & 63;
    size_t row = (size_t)blockIdx.x * 4 + wave;
    const float* xr = x + row * ND + lane * 8;
    float4 a0 = *(const float4*)xr;
    float4 a1 = *(const float4*)(xr + 4);
    float xs[8] = {a0.x, a0.y, a0.z, a0.w, a1.x, a1.y, a1.z, a1.w};
    float s = 0.f;
#pragma unroll
    for (int u = 0; u < 8; ++u) s += xs[u];
#pragma unroll
    for (int off = 32; off; off >>= 1) s += __shfl_xor(s, off);
    float mu = s * (1.0f / ND);
    float ss = 0.f;
#pragma unroll
    for (int u = 0; u < 8; ++u) { xs[u] -= mu; ss += xs[u] * xs[u]; }
#pragma unroll
    for (int off = 32; off; off >>= 1) ss += __shfl_xor(ss, off);
    float rs = rsqrtf(ss * (1.0f / ND) + 1e-5f);
    const float* gp = g + lane * 8;
    const float* bp = bb + lane * 8;
    float4 g0 = *(const float4*)gp, g1 = *(const float4*)(gp + 4);
    float4 c0 = *(const float4*)bp, c1 = *(const float4*)(bp + 4);
    float gg[8] = {g0.x, g0.y, g0.z, g0.w, g1.x, g1.y, g1.z, g1.w};
    float cc[8] = {c0.x, c0.y, c0.z, c0.w, c1.x, c1.y, c1.z, c1.w};
    u32 owh[4], owl[4];
#pragma unroll
    for (int u = 0; u < 4; ++u) {
        float y0 = xs[2 * u] * rs * gg[2 * u] + cc[2 * u];
        float y1 = xs[2 * u + 1] * rs * gg[2 * u + 1] + cc[2 * u + 1];
        u16 h0 = f2bf(y0), h1 = f2bf(y1);
        u16 l0 = f2bf(y0 - bf2f(h0)), l1 = f2bf(y1 - bf2f(h1));
        owh[u] = (u32)h0 | ((u32)h1 << 16);
        owl[u] = (u32)l0 | ((u32)l1 << 16);
    }
    u16* rb = nout + row * 1024;
    *(uint4*)(rb + lane * 8) = make_uint4(owh[0], owh[1], owh[2], owh[3]);
    *(uint4*)(rb + 512 + lane * 8) = make_uint4(owl[0], owl[1], owl[2], owl[3]);
}

// ---------------- residual add + LN2
__global__ __launch_bounds__(256) void resid_ln2_kernel(const float* __restrict__ x,
        const float* __restrict__ h, const float* __restrict__ g,
        const float* __restrict__ bb, float* __restrict__ outb,
        u16* __restrict__ fin) {
    int wave = threadIdx.x >> 6, lane = threadIdx.x & 63;
    size_t row = (size_t)blockIdx.x * 4 + wave;
    const float* xr = x + row * ND + lane * 8;
    const float* hr = h + row * ND + lane * 8;
    float4 a0 = *(const float4*)xr;
    float4 a1 = *(const float4*)(xr + 4);
    float4 h0 = *(const float4*)hr;
    float4 h1 = *(const float4*)(hr + 4);
    float xs[8] = {a0.x + h0.x, a0.y + h0.y, a0.z + h0.z, a0.w + h0.w,
                   a1.x + h1.x, a1.y + h1.y, a1.z + h1.z, a1.w + h1.w};
    float* orow = outb + row * ND + lane * 8;
    *(float4*)orow = make_float4(xs[0], xs[1], xs[2], xs[3]);
    *(float4*)(orow + 4) = make_float4(xs[4], xs[5], xs[6], xs[7]);
    float s = 0.f;
#pragma unroll
    for (int u = 0; u < 8; ++u) s += xs[u];
#pragma unroll
    for (int off = 32; off; off >>= 1) s += __shfl_xor(s, off);
    float mu = s * (1.0f / ND);
    float ss = 0.f;
#pragma unroll
    for (int u = 0; u < 8; ++u) { xs[u] -= mu; ss += xs[u] * xs[u]; }
#pragma unroll
    for (int off = 32; off; off >>= 1) ss += __shfl_xor(ss, off);
    float rs = rsqrtf(ss * (1.0f / ND) + 1e-5f);
    const float* gp = g + lane * 8;
    const float* bp = bb + lane * 8;
    float4 g0 = *(const float4*)gp, g1 = *(const float4*)(gp + 4);
    float4 c0 = *(const float4*)bp, c1 = *(const float4*)(bp + 4);
    float gg[8] = {g0.x, g0.y, g0.z, g0.w, g1.x, g1.y, g1.z, g1.w};
    float cc[8] = {c0.x, c0.y, c0.z, c0.w, c1.x, c1.y, c1.z, c1.w};
    u32 ow[4];
#pragma unroll
    for (int u = 0; u < 4; ++u) {
        float y0 = xs[2 * u] * rs * gg[2 * u] + cc[2 * u];
        float y1 = xs[2 * u + 1] * rs * gg[2 * u + 1] + cc[2 * u + 1];
        ow[u] = (u32)f2bf(y0) | ((u32)f2bf(y1) << 16);
    }
    *(uint4*)(fin + row * ND + lane * 8) = make_uint4(ow[0], ow[1], ow[2], ow[3]);
}

// ---------------- mLSTM recurrence v2: pipelined, transposed gates, XCD-pinned.
// One wave per (b,i); C row in regs (lane j = lane*8..+7). b = blockIdx&7.
__global__ __launch_bounds__(256) void recur_kernel(
        const float* __restrict__ Q, const float* __restrict__ K,
        const float* __restrict__ IT, const float* __restrict__ FT,
        const u16* __restrict__ VT, const u16* __restrict__ OT,
        float* __restrict__ H) {
    int wave = threadIdx.x >> 6, lane = threadIdx.x & 63;
    int gb = blockIdx.x;                   // 0..1023
    int b = gb & 7;                        // XCD pin: batch -> XCD
    int i = ((gb >> 3) << 2) + wave;       // 0..511
    size_t rowb = (size_t)b * NS;
    const float* qp = Q + rowb * ND + lane * 8;
    const float* kp = K + rowb * ND + lane * 8;
    size_t tb = ((size_t)b * ND + i) * NS;
    const float4* itp = (const float4*)(IT + tb);
    const float4* ftp = (const float4*)(FT + tb);
    const uint2*  vtp = (const uint2*)(VT + tb);
    const uint2*  otp = (const uint2*)(OT + tb);
    float* hp = H + rowb * ND + i;
    float c[8];
#pragma unroll
    for (int u = 0; u < 8; ++u) c[u] = 0.f;
    float m = 0.f;
    // prologue loads (t = 0 block)
    float4 k0 = *(const float4*)kp, k1 = *(const float4*)(kp + 4);
    float4 q0 = *(const float4*)qp, q1 = *(const float4*)(qp + 4);
    float4 itq = itp[0], ftq = ftp[0];
    uint2 vq = vtp[0], oq = otp[0];
    for (int t0 = 0; t0 < NS; t0 += 4) {
        int nb = (t0 >> 2) + 1;            // prefetch next gate block (may overrun 16B: safe)
        float4 nit = itp[nb], nft = ftp[nb];
        uint2 nv = vtp[nb], no = otp[nb];
        float it4[4] = {itq.x, itq.y, itq.z, itq.w};
        float ft4[4] = {ftq.x, ftq.y, ftq.z, ftq.w};
        float v4[4] = {bflo(vq.x), bfhi(vq.x), bflo(vq.y), bfhi(vq.y)};
        float o4[4] = {bflo(oq.x), bfhi(oq.x), bflo(oq.y), bfhi(oq.y)};
        float h4[4];
#pragma unroll
        for (int u = 0; u < 4; ++u) {
            float ck[8] = {k0.x, k0.y, k0.z, k0.w, k1.x, k1.y, k1.z, k1.w};
            float cq[8] = {q0.x, q0.y, q0.z, q0.w, q1.x, q1.y, q1.z, q1.w};
            kp += ND; qp += ND;            // prefetch t+1 (overruns 1 row at end: safe)
            k0 = *(const float4*)kp; k1 = *(const float4*)(kp + 4);
            q0 = *(const float4*)qp; q1 = *(const float4*)(qp + 4);
            float mn = fmaxf(ft4[u] + m, it4[u]);
            float ig = __expf(it4[u] - mn);
            float fg = __expf(ft4[u] + m - mn);
            float iv = ig * v4[u] * KSCALE;
            float acc = 0.f;
#pragma unroll
            for (int j = 0; j < 8; ++j) {
                c[j] = fg * c[j] + iv * ck[j];
                acc += c[j] * cq[j];
            }
#pragma unroll
            for (int off = 32; off; off >>= 1) acc += __shfl_xor(acc, off);
            h4[u] = o4[u] * acc;
            m = mn;
        }
        if (lane == 0) {
            hp[(size_t)(t0 + 0) * ND] = h4[0];
            hp[(size_t)(t0 + 1) * ND] = h4[1];
            hp[(size_t)(t0 + 2) * ND] = h4[2];
            hp[(size_t)(t0 + 3) * ND] = h4[3];
        }
        itq = nit; ftq = nft; vq = nv; oq = no;
    }
}

// ---------------- bf16 MFMA GEMM: C[M,N] = A[M,K] @ BT[N,K]^T, fused epilogues
// MODE 0: fused proj (K=1536, A wraps at kwrap=1024) -> Pf slots (transposed gates)
// MODE 1: ffn1 -> gelu(acc+b1) bf16 [M,N]
// MODE 2: ffn2 -> acc + b2 + resid -> f32 [M,N]
#define LP 40   // LDS row pitch in bf16 elems (32 + 8 pad)
template <int MODE>
__global__ __launch_bounds__(256) void gemm_kernel(
        const u16* __restrict__ A, const u16* __restrict__ BT,
        int M, int N, int K, int lda, int ldb, int kwrap,
        const float* __restrict__ bias,
        char* __restrict__ pb,
        float* __restrict__ outf, u16* __restrict__ outh,
        const float* __restrict__ resid) {
    __shared__ u16 As[128 * LP];
    __shared__ u16 Bs[128 * LP];
    int tid = threadIdx.x;
    int wave = tid >> 6, lane = tid & 63;
    int wm = wave >> 1, wn = wave & 1;
    int m0 = blockIdx.y * 128;
    int n0 = blockIdx.x * 128;

    f32x4 acc[4][4];
#pragma unroll
    for (int fi = 0; fi < 4; ++fi)
#pragma unroll
        for (int fj = 0; fj < 4; ++fj)
            acc[fi][fj] = (f32x4){0.f, 0.f, 0.f, 0.f};

    int sr = tid >> 1;            // staging row 0..127
    int sh = (tid & 1) << 4;      // elem offset 0 or 16
    const u16* Ag = A + (size_t)(m0 + sr) * lda + sh;
    const u16* Bg = BT + (size_t)(n0 + sr) * ldb + sh;
    u16* Asw = &As[sr * LP + sh];
    u16* Bsw = &Bs[sr * LP + sh];

    int fr = lane & 15, kb = lane >> 4;
    const u16* Ard = &As[(wm * 64 + fr) * LP + kb * 8];
    const u16* Brd = &Bs[(wn * 64 + fr) * LP + kb * 8];

    for (int k0 = 0; k0 < K; k0 += 32) {
        int ak0 = k0 - (k0 >= kwrap ? kwrap : 0);   // A re-reads nH for k>=kwrap
        uint4 av0 = *(const uint4*)(Ag + ak0);
        uint4 av1 = *(const uint4*)(Ag + ak0 + 8);
        uint4 bv0 = *(const uint4*)(Bg + k0);
        uint4 bv1 = *(const uint4*)(Bg + k0 + 8);
        __syncthreads();
        *(uint4*)Asw = av0;
        *(uint4*)(Asw + 8) = av1;
        *(uint4*)Bsw = bv0;
        *(uint4*)(Bsw + 8) = bv1;
        __syncthreads();
        short8 fa[4], fb[4];
#pragma unroll
        for (int f = 0; f < 4; ++f) {
            fa[f] = *(const short8*)(Ard + f * 16 * LP);
            fb[f] = *(const short8*)(Brd + f * 16 * LP);
        }
#pragma unroll
        for (int fi = 0; fi < 4; ++fi)
#pragma unroll
            for (int fj = 0; fj < 4; ++fj)
                acc[fi][fj] = __builtin_amdgcn_mfma_f32_16x16x32_bf16(
                        fa[fi], fb[fj], acc[fi][fj], 0, 0, 0);
    }

    int rbase = (lane >> 4) * 4;
    int cbase = n0 + wn * 64 + (lane & 15);
#pragma unroll
    for (int fi = 0; fi < 4; ++fi) {
        int r0 = m0 + wm * 64 + fi * 16 + rbase;   // 4 consecutive rows r0..r0+3
#pragma unroll
        for (int fj = 0; fj < 4; ++fj) {
            int col = cbase + fj * 16;
            if (MODE == 0) {
                int p = col >> 9, d = col & 511;
                float bv_ = bias[col];
                float w0 = acc[fi][fj][0] + bv_;
                float w1 = acc[fi][fj][1] + bv_;
                float w2 = acc[fi][fj][2] + bv_;
                float w3 = acc[fi][fj][3] + bv_;
                if (p <= 1) {                      // q,k: [b,t,d] f32
                    float* dst = (float*)(pb + (p ? OFF_K : OFF_Q));
                    dst[(size_t)(r0 + 0) * ND + d] = w0;
                    dst[(size_t)(r0 + 1) * ND + d] = w1;
                    dst[(size_t)(r0 + 2) * ND + d] = w2;
                    dst[(size_t)(r0 + 3) * ND + d] = w3;
                } else {                           // transposed [b,d,t]
                    size_t tb = ((size_t)(r0 >> 11) * ND + d) * NS + (r0 & 2047);
                    if (p == 3) {
                        *(float4*)((float*)(pb + OFF_IT) + tb) =
                                make_float4(w0, w1, w2, w3);
                    } else if (p == 4) {
                        *(float4*)((float*)(pb + OFF_FT) + tb) =
                                make_float4(w0, w1, w2, w3);
                    } else if (p == 2) {           // v bf16
                        uint2 wv = make_uint2((u32)f2bf(w0) | ((u32)f2bf(w1) << 16),
                                              (u32)f2bf(w2) | ((u32)f2bf(w3) << 16));
                        *(uint2*)((u16*)(pb + OFF_V) + tb) = wv;
                    } else {                       // o: sigmoid, bf16
                        float s0 = 1.0f / (1.0f + __expf(-w0));
                        float s1 = 1.0f / (1.0f + __expf(-w1));
                        float s2 = 1.0f / (1.0f + __expf(-w2));
                        float s3 = 1.0f / (1.0f + __expf(-w3));
                        uint2 wv = make_uint2((u32)f2bf(s0) | ((u32)f2bf(s1) << 16),
                                              (u32)f2bf(s2) | ((u32)f2bf(s3) << 16));
                        *(uint2*)((u16*)(pb + OFF_O) + tb) = wv;
                    }
                }
            } else {
#pragma unroll
                for (int r = 0; r < 4; ++r) {
                    int row = r0 + r;
                    float v = acc[fi][fj][r];
                    if (MODE == 1) {
                        float val = v + bias[col];
                        val = 0.5f * val * (1.0f + erff(val * 0.70710678118654752f));
                        outh[(size_t)row * N + col] = f2bf(val);
                    } else {
                        float val = v + bias[col] + resid[(size_t)row * ND + col];
                        outf[(size_t)row * ND + col] = val;
                    }
                }
            }
        }
    }
}

extern "C" void kernel_launch(void* const* d_in, const int* in_sizes, int n_in,
                              void* d_out, int out_size, void* d_ws, size_t ws_size,
                              hipStream_t stream) {
    const float* x    = (const float*)d_in[0];
    const float* ln1g = (const float*)d_in[1];
    const float* ln1b = (const float*)d_in[2];
    const float* ln2g = (const float*)d_in[3];
    const float* ln2b = (const float*)d_in[4];
    const float* Wq = (const float*)d_in[5];
    const float* bq = (const float*)d_in[6];
    const float* Wk = (const float*)d_in[7];
    const float* bk = (const float*)d_in[8];
    const float* Wv = (const float*)d_in[9];
    const float* bv = (const float*)d_in[10];
    const float* Wi = (const float*)d_in[11];
    const float* bi = (const float*)d_in[12];
    const float* Wf = (const float*)d_in[13];
    const float* bfp = (const float*)d_in[14];
    const float* Wo = (const float*)d_in[15];
    const float* bo = (const float*)d_in[16];
    const float* W1 = (const float*)d_in[17];
    const float* b1 = (const float*)d_in[18];
    const float* W2 = (const float*)d_in[19];
    const float* b2 = (const float*)d_in[20];
    float* out = (float*)d_out;

    // ---- workspace layout ----
    char* ws = (char*)d_ws;
    size_t off = 0;
    u16* WcorrT = (u16*)(ws + off); off += (size_t)3072 * 1536 * 2;  // 9 MB [WH|WH|WL]
    u16* W1T    = (u16*)(ws + off); off += (size_t)2048 * 512 * 2;   // 2 MB
    u16* W2T    = (u16*)(ws + off); off += (size_t)512 * 2048 * 2;   // 2 MB
    float* ball = (float*)(ws + off); off += 3072 * 4;               // 12 KB
    off = (off + 255) & ~(size_t)255;
    char* U = ws + off;
    char* Pbase = U;                                  // 160 MB (q,k,it,ft f32; v,o bf16)
    // Acorr [16384][1024] bf16 (32 MB) at U+160MB; Hbuf f32 (32 MB) aliases it
    u16*   Acorr = (u16*)(U + PF_BYTES);
    float* Hbuf  = (float*)(U + PF_BYTES);
    // aliases of dead P (steps 5-7):
    u16* ffnin = (u16*)U;                             // 16 MB
    u16* Gbuf  = (u16*)(U + BSDn * 2);                // 64 MB
    size_t needed = (size_t)(U - ws) + PF_BYTES + (size_t)32 * 1024 * 1024;
    if (ws_size < needed) return;   // graceful fail -> diagnosable as ws shortfall

    // 1. weights
    wcorr_kernel<<<(3072 * 1536) / 256, 256, 0, stream>>>(Wq, Wk, Wv, Wi, Wf, Wo, WcorrT);
    wconv_kernel<<<4096, 256, 0, stream>>>(W1, W1T, 9, 2048, 2048 * 512);
    wconv_kernel<<<4096, 256, 0, stream>>>(W2, W2T, 11, 512, 512 * 2048);
    bias_concat_kernel<<<12, 256, 0, stream>>>(bq, bk, bv, bi, bfp, bo, ball);

    // 2. LN1 -> [nH | nL]
    ln1_kernel<<<NM / 4, 256, 0, stream>>>(x, ln1g, ln1b, Acorr);

    // 3. fused split-precision proj GEMM: K=1536 (nH@WH + nL@WH + nH@WL)
    gemm_kernel<0><<<dim3(3072 / 128, NM / 128), 256, 0, stream>>>(
            Acorr, WcorrT, NM, 3072, 1536, 1024, 1536, 1024, ball,
            Pbase, nullptr, nullptr, nullptr);

    // 4. recurrence
    recur_kernel<<<1024, 256, 0, stream>>>(
            (const float*)(Pbase + OFF_Q), (const float*)(Pbase + OFF_K),
            (const float*)(Pbase + OFF_IT), (const float*)(Pbase + OFF_FT),
            (const u16*)(Pbase + OFF_V), (const u16*)(Pbase + OFF_O), Hbuf);

    // 5. residual + LN2 (out = x + h -> d_out; LN2 -> ffnin)
    resid_ln2_kernel<<<NM / 4, 256, 0, stream>>>(x, Hbuf, ln2g, ln2b, out, ffnin);

    // 6. FFN1: [16384,512] @ [512,2048], gelu
    gemm_kernel<1><<<dim3(2048 / 128, NM / 128), 256, 0, stream>>>(
            ffnin, W1T, NM, 2048, 512, 512, 512, 1 << 30, b1,
            nullptr, nullptr, Gbuf, nullptr);

    // 7. FFN2: [16384,2048] @ [2048,512], + b2 + residual(d_out) -> d_out
    gemm_kernel<2><<<dim3(512 / 128, NM / 128), 256, 0, stream>>>(
            Gbuf, W2T, NM, 512, 2048, 2048, 2048, 1 << 30, b2,
            nullptr, out, nullptr, out);

    (void)in_sizes; (void)n_in; (void)out_size; (void)ws_size;
}

// Round 6
// 763.746 us; speedup vs baseline: 3.2439x; 2.6461x over previous
//
#include <hip/hip_runtime.h>
#include <hip/hip_bf16.h>
#include <cstdint>

typedef unsigned short u16;
typedef unsigned int u32;
typedef __attribute__((ext_vector_type(8))) short short8;
typedef __attribute__((ext_vector_type(4))) float f32x4;

#define NB 8
#define NS 2048
#define ND 512
#define NM (NB * NS)            // 16384 rows
#define CL 64                   // chunk length
#define NCH (NS / CL)           // 32 chunks
static constexpr size_t BSDn = (size_t)NM * ND;   // 8388608 elems
#define KSCALE 0.044194173824159216f              // 1/sqrt(512)

// U-region byte offsets
#define OFF_QB ((size_t)0)            // Qbf  [b,t,d] bf16 16MB
#define OFF_KB (BSDn * 2)             // Kbf  [b,t,d] bf16 (scaled) 16MB
#define OFF_KT (BSDn * 4)             // KT   [b,d,t] bf16 (scaled) 16MB
#define OFF_VT (BSDn * 6)             // VT   [b,d,t] bf16 16MB
#define OFF_OT (BSDn * 8)             // OT   [b,d,t] bf16 (sigmoid) 16MB
#define OFF_IT (BSDn * 10)            // IT   [b,d,t] f32 32MB
#define OFF_FT (BSDn * 14)            // FT   [b,d,t] f32 32MB
#define OFF_G  (BSDn * 18)            // Gm   [b][32][64][64] bf16 2MB
#define OFF_AC (BSDn * 18 + ((size_t)2 << 20))   // Acorr (32MB) / Hbuf alias

__device__ __forceinline__ u16 f2bf(float f) {
    u32 i = __builtin_bit_cast(u32, f);
    u32 r = i + 0x7FFFu + ((i >> 16) & 1u);
    return (u16)(r >> 16);
}
__device__ __forceinline__ float bf2f(u16 h) {
    return __builtin_bit_cast(float, (u32)h << 16);
}

// ---------------- split-precision weight build, [3072][1536] = [WH | WH | WL]
__global__ __launch_bounds__(256) void wcorr_kernel(
        const float* __restrict__ W0, const float* __restrict__ W1,
        const float* __restrict__ W2, const float* __restrict__ W3,
        const float* __restrict__ W4, const float* __restrict__ W5,
        u16* __restrict__ WT) {
    int idx = blockIdx.x * 256 + threadIdx.x;
    int n = idx / 1536, k = idx - n * 1536;
    int p = n >> 9, d = n & 511;
    const float* Wp;
    switch (p) {
        case 0: Wp = W0; break;
        case 1: Wp = W1; break;
        case 2: Wp = W2; break;
        case 3: Wp = W3; break;
        case 4: Wp = W4; break;
        default: Wp = W5; break;
    }
    u16 o;
    if (k < 1024) {
        o = f2bf(Wp[(size_t)(k & 511) * 512 + d]);
    } else {
        float w = Wp[(size_t)(k - 1024) * 512 + d];
        o = f2bf(w - bf2f(f2bf(w)));
    }
    WT[idx] = o;
}

__global__ __launch_bounds__(256) void wconv_kernel(const float* __restrict__ W,
        u16* __restrict__ WT, int lk, int N, int total) {
    int idx = blockIdx.x * 256 + threadIdx.x;
    if (idx >= total) return;
    int n = idx >> lk;
    int k = idx & ((1 << lk) - 1);
    WT[idx] = f2bf(W[(size_t)k * N + n]);
}

__global__ __launch_bounds__(256) void bias_concat_kernel(
        const float* b0, const float* b1, const float* b2,
        const float* b3, const float* b4, const float* b5,
        float* __restrict__ ball) {
    int idx = blockIdx.x * 256 + threadIdx.x;
    if (idx >= 3072) return;
    int p = idx >> 9, d = idx & 511;
    float v;
    switch (p) {
        case 0: v = b0[d]; break;
        case 1: v = b1[d]; break;
        case 2: v = b2[d]; break;
        case 3: v = b3[d]; break;
        case 4: v = b4[d]; break;
        default: v = b5[d]; break;
    }
    ball[idx] = v;
}

// ---------------- LN1: x -> Acorr [16384][1024] = [nH | nL]
__global__ __launch_bounds__(256) void ln1_kernel(const float* __restrict__ x,
        const float* __restrict__ g, const float* __restrict__ bb,
        u16* __restrict__ nout) {
    int wave = threadIdx.x >> 6, lane = threadIdx.x & 63;
    size_t row = (size_t)blockIdx.x * 4 + wave;
    const float* xr = x + row * ND + lane * 8;
    float4 a0 = *(const float4*)xr;
    float4 a1 = *(const float4*)(xr + 4);
    float xs[8] = {a0.x, a0.y, a0.z, a0.w, a1.x, a1.y, a1.z, a1.w};
    float s = 0.f;
#pragma unroll
    for (int u = 0; u < 8; ++u) s += xs[u];
#pragma unroll
    for (int off = 32; off; off >>= 1) s += __shfl_xor(s, off);
    float mu = s * (1.0f / ND);
    float ss = 0.f;
#pragma unroll
    for (int u = 0; u < 8; ++u) { xs[u] -= mu; ss += xs[u] * xs[u]; }
#pragma unroll
    for (int off = 32; off; off >>= 1) ss += __shfl_xor(ss, off);
    float rs = rsqrtf(ss * (1.0f / ND) + 1e-5f);
    const float* gp = g + lane * 8;
    const float* bp = bb + lane * 8;
    float4 g0 = *(const float4*)gp, g1 = *(const float4*)(gp + 4);
    float4 c0 = *(const float4*)bp, c1 = *(const float4*)(bp + 4);
    float gg[8] = {g0.x, g0.y, g0.z, g0.w, g1.x, g1.y, g1.z, g1.w};
    float cc[8] = {c0.x, c0.y, c0.z, c0.w, c1.x, c1.y, c1.z, c1.w};
    u32 owh[4], owl[4];
#pragma unroll
    for (int u = 0; u < 4; ++u) {
        float y0 = xs[2 * u] * rs * gg[2 * u] + cc[2 * u];
        float y1 = xs[2 * u + 1] * rs * gg[2 * u + 1] + cc[2 * u + 1];
        u16 h0 = f2bf(y0), h1 = f2bf(y1);
        u16 l0 = f2bf(y0 - bf2f(h0)), l1 = f2bf(y1 - bf2f(h1));
        owh[u] = (u32)h0 | ((u32)h1 << 16);
        owl[u] = (u32)l0 | ((u32)l1 << 16);
    }
    u16* rb = nout + row * 1024;
    *(uint4*)(rb + lane * 8) = make_uint4(owh[0], owh[1], owh[2], owh[3]);
    *(uint4*)(rb + 512 + lane * 8) = make_uint4(owl[0], owl[1], owl[2], owl[3]);
}

// ---------------- residual add + LN2
__global__ __launch_bounds__(256) void resid_ln2_kernel(const float* __restrict__ x,
        const float* __restrict__ h, const float* __restrict__ g,
        const float* __restrict__ bb, float* __restrict__ outb,
        u16* __restrict__ fin) {
    int wave = threadIdx.x >> 6, lane = threadIdx.x & 63;
    size_t row = (size_t)blockIdx.x * 4 + wave;
    const float* xr = x + row * ND + lane * 8;
    const float* hr = h + row * ND + lane * 8;
    float4 a0 = *(const float4*)xr;
    float4 a1 = *(const float4*)(xr + 4);
    float4 h0 = *(const float4*)hr;
    float4 h1 = *(const float4*)(hr + 4);
    float xs[8] = {a0.x + h0.x, a0.y + h0.y, a0.z + h0.z, a0.w + h0.w,
                   a1.x + h1.x, a1.y + h1.y, a1.z + h1.z, a1.w + h1.w};
    float* orow = outb + row * ND + lane * 8;
    *(float4*)orow = make_float4(xs[0], xs[1], xs[2], xs[3]);
    *(float4*)(orow + 4) = make_float4(xs[4], xs[5], xs[6], xs[7]);
    float s = 0.f;
#pragma unroll
    for (int u = 0; u < 8; ++u) s += xs[u];
#pragma unroll
    for (int off = 32; off; off >>= 1) s += __shfl_xor(s, off);
    float mu = s * (1.0f / ND);
    float ss = 0.f;
#pragma unroll
    for (int u = 0; u < 8; ++u) { xs[u] -= mu; ss += xs[u] * xs[u]; }
#pragma unroll
    for (int off = 32; off; off >>= 1) ss += __shfl_xor(ss, off);
    float rs = rsqrtf(ss * (1.0f / ND) + 1e-5f);
    const float* gp = g + lane * 8;
    const float* bp = bb + lane * 8;
    float4 g0 = *(const float4*)gp, g1 = *(const float4*)(gp + 4);
    float4 c0 = *(const float4*)bp, c1 = *(const float4*)(bp + 4);
    float gg[8] = {g0.x, g0.y, g0.z, g0.w, g1.x, g1.y, g1.z, g1.w};
    float cc[8] = {c0.x, c0.y, c0.z, c0.w, c1.x, c1.y, c1.z, c1.w};
    u32 ow[4];
#pragma unroll
    for (int u = 0; u < 4; ++u) {
        float y0 = xs[2 * u] * rs * gg[2 * u] + cc[2 * u];
        float y1 = xs[2 * u + 1] * rs * gg[2 * u + 1] + cc[2 * u + 1];
        ow[u] = (u32)f2bf(y0) | ((u32)f2bf(y1) << 16);
    }
    *(uint4*)(fin + row * ND + lane * 8) = make_uint4(ow[0], ow[1], ow[2], ow[3]);
}

// ---------------- G kernel: Gm[b,c,t,s] = tril(Q_chunk @ K_chunk^T), bf16
__global__ __launch_bounds__(256) void gqk_kernel(
        const u16* __restrict__ Qb, const u16* __restrict__ Kb,
        u16* __restrict__ Gm) {
    __shared__ u16 Qs[64][520];
    __shared__ u16 Ks[64][520];
    int tid = threadIdx.x;
    int w = tid >> 6, lane = tid & 63;
    int b = blockIdx.x >> 5, c = blockIdx.x & 31;
    int t0 = c * CL;
    {
        int row = tid >> 2, cb = (tid & 3) * 128;
        const u16* qsrc = Qb + ((size_t)b * NS + t0 + row) * ND + cb;
        const u16* ksrc = Kb + ((size_t)b * NS + t0 + row) * ND + cb;
#pragma unroll
        for (int u = 0; u < 16; ++u) {          // FIX: short8 = 8 elems, step 8
            *(short8*)&Qs[row][cb + u * 8] = *(const short8*)(qsrc + u * 8);
            *(short8*)&Ks[row][cb + u * 8] = *(const short8*)(ksrc + u * 8);
        }
    }
    __syncthreads();
    int qw = lane & 15, kg = lane >> 4;
    f32x4 ga[4];
#pragma unroll
    for (int ns = 0; ns < 4; ++ns) ga[ns] = (f32x4){0.f, 0.f, 0.f, 0.f};
    for (int kb = 0; kb < 16; ++kb) {
        short8 aq = *(const short8*)&Qs[(w << 4) + qw][kb * 32 + (kg << 3)];
#pragma unroll
        for (int ns = 0; ns < 4; ++ns) {
            short8 bk = *(const short8*)&Ks[(ns << 4) + qw][kb * 32 + (kg << 3)];
            ga[ns] = __builtin_amdgcn_mfma_f32_16x16x32_bf16(aq, bk, ga[ns], 0, 0, 0);
        }
    }
    u16* gout = Gm + (size_t)(b * NCH + c) * CL * CL;
#pragma unroll
    for (int ns = 0; ns < 4; ++ns) {
#pragma unroll
        for (int rg = 0; rg < 4; ++rg) {
            int t = (w << 4) + (kg << 2) + rg;
            int s = (ns << 4) + qw;
            gout[t * CL + s] = (s <= t) ? f2bf(ga[ns][rg]) : (u16)0;
        }
    }
}

// ---------------- chunked mLSTM recurrence. wg = (batch b, i-slice of 16).
// State C[16i x 512j] f32 lives in MFMA accumulators; m_old in LDS.
__global__ __launch_bounds__(256) void recur_kernel(
        const u16* __restrict__ Qb, const u16* __restrict__ KT,
        const u16* __restrict__ Gm,
        const float* __restrict__ IT, const float* __restrict__ FT,
        const u16* __restrict__ VT, const u16* __restrict__ OT,
        float* __restrict__ H) {
    __shared__ u16 Chi[16][520];
    __shared__ u16 Clo[16][520];
    __shared__ u16 Ub[16][72];
    __shared__ float A1[64][21];
    __shared__ float A2[64][21];
    __shared__ float gam[16];
    __shared__ float mold[16];
    int tid = threadIdx.x;
    int w = tid >> 6, lane = tid & 63;
    int b = blockIdx.x >> 5;
    int i0 = (blockIdx.x & 31) << 4;
    int qw = lane & 15, kg = lane >> 4;
    if (tid < 16) mold[tid] = 0.f;
    f32x4 cacc[8];
#pragma unroll
    for (int n = 0; n < 8; ++n) cacc[n] = (f32x4){0.f, 0.f, 0.f, 0.f};
    __syncthreads();

    size_t bT = (size_t)b * NS;
    size_t bD = (size_t)b * ND;

    for (int c = 0; c < NCH; ++c) {
        int t0 = c * CL;
        // ---- phase 1: gate scan (4 i's per wave, lane = step)
        for (int r = 0; r < 4; ++r) {
            int il = (w << 2) + r;
            size_t gofs = (bD + i0 + il) * NS + t0 + lane;
            float ft = FT[gofs];
            float it = IT[gofs];
            float vv = bf2f(VT[gofs]);
            float bs = ft;
#pragma unroll
            for (int o = 1; o < 64; o <<= 1) {
                float nv = __shfl_up(bs, o);
                if (lane >= o) bs += nv;
            }
            float e = it - bs;
            float Mv = e;
#pragma unroll
            for (int o = 1; o < 64; o <<= 1) {
                float nv = __shfl_up(Mv, o);
                if (lane >= o) Mv = fmaxf(Mv, nv);
            }
            float mo = mold[il];
            Mv = fmaxf(Mv, mo);
            float E = __shfl(Mv, 63);
            Ub[il][lane] = f2bf(__expf(e - E) * vv);
            A1[lane][il] = __expf(mo - Mv);
            A2[lane][il] = __expf(fminf(E - Mv, 80.f));   // clamp: no inf
            if (lane == 63) {
                gam[il] = __expf(mo - E);
                mold[il] = bs + E;
            }
        }
        // ---- stage C_old to LDS as bf16 hi/lo
#pragma unroll
        for (int n = 0; n < 8; ++n) {
            int j = (w << 7) + (n << 4) + qw;
#pragma unroll
            for (int rg = 0; rg < 4; ++rg) {
                int irow = (kg << 2) + rg;
                float cv = cacc[n][rg];
                u16 hi = f2bf(cv);
                Chi[irow][j] = hi;
                Clo[irow][j] = f2bf(cv - bf2f(hi));
            }
        }
        __syncthreads();

        // ---- phase 2a: QC = Q @ C_old^T (hi + lo), wave w owns t in [w*16, w*16+16)
        f32x4 qch = (f32x4){0.f, 0.f, 0.f, 0.f};
        f32x4 qcl = (f32x4){0.f, 0.f, 0.f, 0.f};
        {
            const u16* qrow = Qb + (bT + t0 + (w << 4) + qw) * ND + (kg << 3);
#pragma unroll
            for (int kb = 0; kb < 16; ++kb) {
                short8 aq = *(const short8*)(qrow + kb * 32);
                short8 bh = *(const short8*)&Chi[qw][kb * 32 + (kg << 3)];
                short8 bl = *(const short8*)&Clo[qw][kb * 32 + (kg << 3)];
                qch = __builtin_amdgcn_mfma_f32_16x16x32_bf16(aq, bh, qch, 0, 0, 0);
                qcl = __builtin_amdgcn_mfma_f32_16x16x32_bf16(aq, bl, qcl, 0, 0, 0);
            }
        }
        // ---- phase 2b: intra = tril(G) @ U
        f32x4 pin = (f32x4){0.f, 0.f, 0.f, 0.f};
        {
            const u16* grow = Gm + ((size_t)(b * NCH + c) * CL + (w << 4) + qw) * CL + (kg << 3);
#pragma unroll
            for (int kb = 0; kb < 2; ++kb) {
                short8 ag = *(const short8*)(grow + kb * 32);
                short8 bu = *(const short8*)&Ub[qw][kb * 32 + (kg << 3)];
                pin = __builtin_amdgcn_mfma_f32_16x16x32_bf16(ag, bu, pin, 0, 0, 0);
            }
        }
        // ---- phase 2c: C = gamma*C + U^T @ K
        {
            float g[4];
#pragma unroll
            for (int rg = 0; rg < 4; ++rg) g[rg] = gam[(kg << 2) + rg];
#pragma unroll
            for (int n = 0; n < 8; ++n) {
#pragma unroll
                for (int rg = 0; rg < 4; ++rg) cacc[n][rg] *= g[rg];
            }
#pragma unroll
            for (int kb = 0; kb < 2; ++kb) {
                short8 au = *(const short8*)&Ub[qw][kb * 32 + (kg << 3)];
#pragma unroll
                for (int n = 0; n < 8; ++n) {
                    const u16* krow = KT + (bD + (w << 7) + (n << 4) + qw) * NS
                                      + t0 + kb * 32 + (kg << 3);
                    short8 bk = *(const short8*)krow;
                    cacc[n] = __builtin_amdgcn_mfma_f32_16x16x32_bf16(au, bk, cacc[n], 0, 0, 0);
                }
            }
        }
        // ---- phase 3: h = o * (A1*QC + A2*intra)
#pragma unroll
        for (int rg = 0; rg < 4; ++rg) {
            int tl = (w << 4) + (kg << 2) + rg;
            float o = bf2f(OT[(bD + i0 + qw) * NS + t0 + tl]);
            float h = o * (A1[tl][qw] * (qch[rg] + qcl[rg]) + A2[tl][qw] * pin[rg]);
            H[(bT + t0 + tl) * ND + i0 + qw] = h;
        }
        __syncthreads();
    }
}

// ---------------- bf16 MFMA GEMM with fused epilogues
#define LP 40
template <int MODE>
__global__ __launch_bounds__(256) void gemm_kernel(
        const u16* __restrict__ A, const u16* __restrict__ BT,
        int M, int N, int K, int lda, int ldb, int kwrap,
        const float* __restrict__ bias,
        char* __restrict__ pb,
        float* __restrict__ outf, u16* __restrict__ outh,
        const float* __restrict__ resid) {
    __shared__ u16 As[128 * LP];
    __shared__ u16 Bs[128 * LP];
    int tid = threadIdx.x;
    int wave = tid >> 6, lane = tid & 63;
    int wm = wave >> 1, wn = wave & 1;
    int m0 = blockIdx.y * 128;
    int n0 = blockIdx.x * 128;

    f32x4 acc[4][4];
#pragma unroll
    for (int fi = 0; fi < 4; ++fi)
#pragma unroll
        for (int fj = 0; fj < 4; ++fj)
            acc[fi][fj] = (f32x4){0.f, 0.f, 0.f, 0.f};

    int sr = tid >> 1;
    int sh = (tid & 1) << 4;
    const u16* Ag = A + (size_t)(m0 + sr) * lda + sh;
    const u16* Bg = BT + (size_t)(n0 + sr) * ldb + sh;
    u16* Asw = &As[sr * LP + sh];
    u16* Bsw = &Bs[sr * LP + sh];

    int fr = lane & 15, kb = lane >> 4;
    const u16* Ard = &As[(wm * 64 + fr) * LP + kb * 8];
    const u16* Brd = &Bs[(wn * 64 + fr) * LP + kb * 8];

    for (int k0 = 0; k0 < K; k0 += 32) {
        int ak0 = k0 - (k0 >= kwrap ? kwrap : 0);
        uint4 av0 = *(const uint4*)(Ag + ak0);
        uint4 av1 = *(const uint4*)(Ag + ak0 + 8);
        uint4 bv0 = *(const uint4*)(Bg + k0);
        uint4 bv1 = *(const uint4*)(Bg + k0 + 8);
        __syncthreads();
        *(uint4*)Asw = av0;
        *(uint4*)(Asw + 8) = av1;
        *(uint4*)Bsw = bv0;
        *(uint4*)(Bsw + 8) = bv1;
        __syncthreads();
        short8 fa[4], fb[4];
#pragma unroll
        for (int f = 0; f < 4; ++f) {
            fa[f] = *(const short8*)(Ard + f * 16 * LP);
            fb[f] = *(const short8*)(Brd + f * 16 * LP);
        }
#pragma unroll
        for (int fi = 0; fi < 4; ++fi)
#pragma unroll
            for (int fj = 0; fj < 4; ++fj)
                acc[fi][fj] = __builtin_amdgcn_mfma_f32_16x16x32_bf16(
                        fa[fi], fb[fj], acc[fi][fj], 0, 0, 0);
    }

    int rbase = (lane >> 4) * 4;
    int cbase = n0 + wn * 64 + (lane & 15);
#pragma unroll
    for (int fi = 0; fi < 4; ++fi) {
        int r0 = m0 + wm * 64 + fi * 16 + rbase;
#pragma unroll
        for (int fj = 0; fj < 4; ++fj) {
            int col = cbase + fj * 16;
            if (MODE == 0) {
                int p = col >> 9, d = col & 511;
                float bv_ = bias[col];
                float w0 = acc[fi][fj][0] + bv_;
                float w1 = acc[fi][fj][1] + bv_;
                float w2 = acc[fi][fj][2] + bv_;
                float w3 = acc[fi][fj][3] + bv_;
                size_t tb = ((size_t)(r0 >> 11) * ND + d) * NS + (r0 & 2047);
                if (p == 0) {
                    u16* q = (u16*)(pb + OFF_QB);
                    q[(size_t)(r0 + 0) * ND + d] = f2bf(w0);
                    q[(size_t)(r0 + 1) * ND + d] = f2bf(w1);
                    q[(size_t)(r0 + 2) * ND + d] = f2bf(w2);
                    q[(size_t)(r0 + 3) * ND + d] = f2bf(w3);
                } else if (p == 1) {
                    float s0 = w0 * KSCALE, s1 = w1 * KSCALE;
                    float s2 = w2 * KSCALE, s3 = w3 * KSCALE;
                    u16* kbuf = (u16*)(pb + OFF_KB);
                    kbuf[(size_t)(r0 + 0) * ND + d] = f2bf(s0);
                    kbuf[(size_t)(r0 + 1) * ND + d] = f2bf(s1);
                    kbuf[(size_t)(r0 + 2) * ND + d] = f2bf(s2);
                    kbuf[(size_t)(r0 + 3) * ND + d] = f2bf(s3);
                    uint2 wv = make_uint2((u32)f2bf(s0) | ((u32)f2bf(s1) << 16),
                                          (u32)f2bf(s2) | ((u32)f2bf(s3) << 16));
                    *(uint2*)((u16*)(pb + OFF_KT) + tb) = wv;
                } else if (p == 3) {
                    *(float4*)((float*)(pb + OFF_IT) + tb) = make_float4(w0, w1, w2, w3);
                } else if (p == 4) {
                    *(float4*)((float*)(pb + OFF_FT) + tb) = make_float4(w0, w1, w2, w3);
                } else if (p == 2) {
                    uint2 wv = make_uint2((u32)f2bf(w0) | ((u32)f2bf(w1) << 16),
                                          (u32)f2bf(w2) | ((u32)f2bf(w3) << 16));
                    *(uint2*)((u16*)(pb + OFF_VT) + tb) = wv;
                } else {
                    float s0 = 1.0f / (1.0f + __expf(-w0));
                    float s1 = 1.0f / (1.0f + __expf(-w1));
                    float s2 = 1.0f / (1.0f + __expf(-w2));
                    float s3 = 1.0f / (1.0f + __expf(-w3));
                    uint2 wv = make_uint2((u32)f2bf(s0) | ((u32)f2bf(s1) << 16),
                                          (u32)f2bf(s2) | ((u32)f2bf(s3) << 16));
                    *(uint2*)((u16*)(pb + OFF_OT) + tb) = wv;
                }
            } else {
#pragma unroll
                for (int r = 0; r < 4; ++r) {
                    int row = r0 + r;
                    float v = acc[fi][fj][r];
                    if (MODE == 1) {
                        float val = v + bias[col];
                        val = 0.5f * val * (1.0f + erff(val * 0.70710678118654752f));
                        outh[(size_t)row * N + col] = f2bf(val);
                    } else {
                        float val = v + bias[col] + resid[(size_t)row * ND + col];
                        outf[(size_t)row * ND + col] = val;
                    }
                }
            }
        }
    }
}

extern "C" void kernel_launch(void* const* d_in, const int* in_sizes, int n_in,
                              void* d_out, int out_size, void* d_ws, size_t ws_size,
                              hipStream_t stream) {
    const float* x    = (const float*)d_in[0];
    const float* ln1g = (const float*)d_in[1];
    const float* ln1b = (const float*)d_in[2];
    const float* ln2g = (const float*)d_in[3];
    const float* ln2b = (const float*)d_in[4];
    const float* Wq = (const float*)d_in[5];
    const float* bq = (const float*)d_in[6];
    const float* Wk = (const float*)d_in[7];
    const float* bk = (const float*)d_in[8];
    const float* Wv = (const float*)d_in[9];
    const float* bv = (const float*)d_in[10];
    const float* Wi = (const float*)d_in[11];
    const float* bi = (const float*)d_in[12];
    const float* Wf = (const float*)d_in[13];
    const float* bfp = (const float*)d_in[14];
    const float* Wo = (const float*)d_in[15];
    const float* bo = (const float*)d_in[16];
    const float* W1 = (const float*)d_in[17];
    const float* b1 = (const float*)d_in[18];
    const float* W2 = (const float*)d_in[19];
    const float* b2 = (const float*)d_in[20];
    float* out = (float*)d_out;

    char* ws = (char*)d_ws;
    size_t off = 0;
    u16* WcorrT = (u16*)(ws + off); off += (size_t)3072 * 1536 * 2;  // 9 MB
    u16* W1T    = (u16*)(ws + off); off += (size_t)2048 * 512 * 2;   // 2 MB
    u16* W2T    = (u16*)(ws + off); off += (size_t)512 * 2048 * 2;   // 2 MB
    float* ball = (float*)(ws + off); off += 3072 * 4;
    off = (off + 255) & ~(size_t)255;
    char* U = ws + off;
    u16*   Acorr = (u16*)(U + OFF_AC);
    float* Hbuf  = (float*)(U + OFF_AC);
    u16* ffnin = (u16*)U;                       // aliases dead Qbf
    u16* Gbuf  = (u16*)(U + OFF_KB);            // aliases dead Kbf/KT/VT/OT
    size_t needed = (size_t)(U - ws) + OFF_AC + (size_t)32 * 1024 * 1024;
    if (ws_size < needed) return;

    // 1. weights
    wcorr_kernel<<<(3072 * 1536) / 256, 256, 0, stream>>>(Wq, Wk, Wv, Wi, Wf, Wo, WcorrT);
    wconv_kernel<<<4096, 256, 0, stream>>>(W1, W1T, 9, 2048, 2048 * 512);
    wconv_kernel<<<4096, 256, 0, stream>>>(W2, W2T, 11, 512, 512 * 2048);
    bias_concat_kernel<<<12, 256, 0, stream>>>(bq, bk, bv, bi, bfp, bo, ball);

    // 2. LN1 -> [nH | nL]
    ln1_kernel<<<NM / 4, 256, 0, stream>>>(x, ln1g, ln1b, Acorr);

    // 3. fused split-precision proj GEMM: K=1536
    gemm_kernel<0><<<dim3(3072 / 128, NM / 128), 256, 0, stream>>>(
            Acorr, WcorrT, NM, 3072, 1536, 1024, 1536, 1024, ball,
            U, nullptr, nullptr, nullptr);

    // 4a. G = tril(Q K^T) per (batch, chunk)
    gqk_kernel<<<NB * NCH, 256, 0, stream>>>(
            (const u16*)(U + OFF_QB), (const u16*)(U + OFF_KB), (u16*)(U + OFF_G));

    // 4b. chunked recurrence
    recur_kernel<<<NB * 32, 256, 0, stream>>>(
            (const u16*)(U + OFF_QB), (const u16*)(U + OFF_KT), (const u16*)(U + OFF_G),
            (const float*)(U + OFF_IT), (const float*)(U + OFF_FT),
            (const u16*)(U + OFF_VT), (const u16*)(U + OFF_OT), Hbuf);

    // 5. residual + LN2
    resid_ln2_kernel<<<NM / 4, 256, 0, stream>>>(x, Hbuf, ln2g, ln2b, out, ffnin);

    // 6. FFN1
    gemm_kernel<1><<<dim3(2048 / 128, NM / 128), 256, 0, stream>>>(
            ffnin, W1T, NM, 2048, 512, 512, 512, 1 << 30, b1,
            nullptr, nullptr, Gbuf, nullptr);

    // 7. FFN2
    gemm_kernel<2><<<dim3(512 / 128, NM / 128), 256, 0, stream>>>(
            Gbuf, W2T, NM, 512, 2048, 2048, 2048, 1 << 30, b2,
            nullptr, out, nullptr, out);

    (void)in_sizes; (void)n_in; (void)out_size; (void)ws_size;
}

// Round 7
// 732.949 us; speedup vs baseline: 3.3802x; 1.0420x over previous
//
#include <hip/hip_runtime.h>
#include <hip/hip_bf16.h>
#include <cstdint>

typedef unsigned short u16;
typedef unsigned int u32;
typedef __attribute__((ext_vector_type(8))) short short8;
typedef __attribute__((ext_vector_type(4))) float f32x4;

#define NB 8
#define NS 2048
#define ND 512
#define NM (NB * NS)            // 16384 rows
#define CL 64                   // chunk length
#define NCH (NS / CL)           // 32 chunks
static constexpr size_t BSDn = (size_t)NM * ND;   // 8388608 elems
#define KSCALE 0.044194173824159216f              // 1/sqrt(512)

// U-region byte offsets
#define OFF_QB ((size_t)0)            // Qbf  [b,t,d] bf16 16MB
#define OFF_KB (BSDn * 2)             // Kbf  [b,t,d] bf16 (scaled) 16MB
#define OFF_KT (BSDn * 4)             // KT   [b,d,t] bf16 (scaled) 16MB
#define OFF_VT (BSDn * 6)             // VT   [b,d,t] bf16 16MB
#define OFF_OT (BSDn * 8)             // OT   [b,d,t] bf16 (sigmoid) 16MB
#define OFF_IT (BSDn * 10)            // IT   [b,d,t] f32 32MB
#define OFF_FT (BSDn * 14)            // FT   [b,d,t] f32 32MB
#define OFF_G  (BSDn * 18)            // Gm   [b][32][64][64] bf16 2MB
#define OFF_AC (BSDn * 18 + ((size_t)2 << 20))   // Acorr (32MB) / Hbuf alias

typedef __attribute__((address_space(1))) const u32 gas_u32;
typedef __attribute__((address_space(3))) u32 las_u32;

__device__ __forceinline__ u16 f2bf(float f) {
    u32 i = __builtin_bit_cast(u32, f);
    u32 r = i + 0x7FFFu + ((i >> 16) & 1u);
    return (u16)(r >> 16);
}
__device__ __forceinline__ float bf2f(u16 h) {
    return __builtin_bit_cast(float, (u32)h << 16);
}

// ---------------- split-precision weight build, [3072][1536] = [WH | WH | WL]
__global__ __launch_bounds__(256) void wcorr_kernel(
        const float* __restrict__ W0, const float* __restrict__ W1,
        const float* __restrict__ W2, const float* __restrict__ W3,
        const float* __restrict__ W4, const float* __restrict__ W5,
        u16* __restrict__ WT) {
    int idx = blockIdx.x * 256 + threadIdx.x;
    int n = idx / 1536, k = idx - n * 1536;
    int p = n >> 9, d = n & 511;
    const float* Wp;
    switch (p) {
        case 0: Wp = W0; break;
        case 1: Wp = W1; break;
        case 2: Wp = W2; break;
        case 3: Wp = W3; break;
        case 4: Wp = W4; break;
        default: Wp = W5; break;
    }
    u16 o;
    if (k < 1024) {
        o = f2bf(Wp[(size_t)(k & 511) * 512 + d]);
    } else {
        float w = Wp[(size_t)(k - 1024) * 512 + d];
        o = f2bf(w - bf2f(f2bf(w)));
    }
    WT[idx] = o;
}

__global__ __launch_bounds__(256) void wconv_kernel(const float* __restrict__ W,
        u16* __restrict__ WT, int lk, int N, int total) {
    int idx = blockIdx.x * 256 + threadIdx.x;
    if (idx >= total) return;
    int n = idx >> lk;
    int k = idx & ((1 << lk) - 1);
    WT[idx] = f2bf(W[(size_t)k * N + n]);
}

__global__ __launch_bounds__(256) void bias_concat_kernel(
        const float* b0, const float* b1, const float* b2,
        const float* b3, const float* b4, const float* b5,
        float* __restrict__ ball) {
    int idx = blockIdx.x * 256 + threadIdx.x;
    if (idx >= 3072) return;
    int p = idx >> 9, d = idx & 511;
    float v;
    switch (p) {
        case 0: v = b0[d]; break;
        case 1: v = b1[d]; break;
        case 2: v = b2[d]; break;
        case 3: v = b3[d]; break;
        case 4: v = b4[d]; break;
        default: v = b5[d]; break;
    }
    ball[idx] = v;
}

// ---------------- LN1: x -> Acorr [16384][1024] = [nH | nL]
__global__ __launch_bounds__(256) void ln1_kernel(const float* __restrict__ x,
        const float* __restrict__ g, const float* __restrict__ bb,
        u16* __restrict__ nout) {
    int wave = threadIdx.x >> 6, lane = threadIdx.x & 63;
    size_t row = (size_t)blockIdx.x * 4 + wave;
    const float* xr = x + row * ND + lane * 8;
    float4 a0 = *(const float4*)xr;
    float4 a1 = *(const float4*)(xr + 4);
    float xs[8] = {a0.x, a0.y, a0.z, a0.w, a1.x, a1.y, a1.z, a1.w};
    float s = 0.f;
#pragma unroll
    for (int u = 0; u < 8; ++u) s += xs[u];
#pragma unroll
    for (int off = 32; off; off >>= 1) s += __shfl_xor(s, off);
    float mu = s * (1.0f / ND);
    float ss = 0.f;
#pragma unroll
    for (int u = 0; u < 8; ++u) { xs[u] -= mu; ss += xs[u] * xs[u]; }
#pragma unroll
    for (int off = 32; off; off >>= 1) ss += __shfl_xor(ss, off);
    float rs = rsqrtf(ss * (1.0f / ND) + 1e-5f);
    const float* gp = g + lane * 8;
    const float* bp = bb + lane * 8;
    float4 g0 = *(const float4*)gp, g1 = *(const float4*)(gp + 4);
    float4 c0 = *(const float4*)bp, c1 = *(const float4*)(bp + 4);
    float gg[8] = {g0.x, g0.y, g0.z, g0.w, g1.x, g1.y, g1.z, g1.w};
    float cc[8] = {c0.x, c0.y, c0.z, c0.w, c1.x, c1.y, c1.z, c1.w};
    u32 owh[4], owl[4];
#pragma unroll
    for (int u = 0; u < 4; ++u) {
        float y0 = xs[2 * u] * rs * gg[2 * u] + cc[2 * u];
        float y1 = xs[2 * u + 1] * rs * gg[2 * u + 1] + cc[2 * u + 1];
        u16 h0 = f2bf(y0), h1 = f2bf(y1);
        u16 l0 = f2bf(y0 - bf2f(h0)), l1 = f2bf(y1 - bf2f(h1));
        owh[u] = (u32)h0 | ((u32)h1 << 16);
        owl[u] = (u32)l0 | ((u32)l1 << 16);
    }
    u16* rb = nout + row * 1024;
    *(uint4*)(rb + lane * 8) = make_uint4(owh[0], owh[1], owh[2], owh[3]);
    *(uint4*)(rb + 512 + lane * 8) = make_uint4(owl[0], owl[1], owl[2], owl[3]);
}

// ---------------- residual add + LN2
__global__ __launch_bounds__(256) void resid_ln2_kernel(const float* __restrict__ x,
        const float* __restrict__ h, const float* __restrict__ g,
        const float* __restrict__ bb, float* __restrict__ outb,
        u16* __restrict__ fin) {
    int wave = threadIdx.x >> 6, lane = threadIdx.x & 63;
    size_t row = (size_t)blockIdx.x * 4 + wave;
    const float* xr = x + row * ND + lane * 8;
    const float* hr = h + row * ND + lane * 8;
    float4 a0 = *(const float4*)xr;
    float4 a1 = *(const float4*)(xr + 4);
    float4 h0 = *(const float4*)hr;
    float4 h1 = *(const float4*)(hr + 4);
    float xs[8] = {a0.x + h0.x, a0.y + h0.y, a0.z + h0.z, a0.w + h0.w,
                   a1.x + h1.x, a1.y + h1.y, a1.z + h1.z, a1.w + h1.w};
    float* orow = outb + row * ND + lane * 8;
    *(float4*)orow = make_float4(xs[0], xs[1], xs[2], xs[3]);
    *(float4*)(orow + 4) = make_float4(xs[4], xs[5], xs[6], xs[7]);
    float s = 0.f;
#pragma unroll
    for (int u = 0; u < 8; ++u) s += xs[u];
#pragma unroll
    for (int off = 32; off; off >>= 1) s += __shfl_xor(s, off);
    float mu = s * (1.0f / ND);
    float ss = 0.f;
#pragma unroll
    for (int u = 0; u < 8; ++u) { xs[u] -= mu; ss += xs[u] * xs[u]; }
#pragma unroll
    for (int off = 32; off; off >>= 1) ss += __shfl_xor(ss, off);
    float rs = rsqrtf(ss * (1.0f / ND) + 1e-5f);
    const float* gp = g + lane * 8;
    const float* bp = bb + lane * 8;
    float4 g0 = *(const float4*)gp, g1 = *(const float4*)(gp + 4);
    float4 c0 = *(const float4*)bp, c1 = *(const float4*)(bp + 4);
    float gg[8] = {g0.x, g0.y, g0.z, g0.w, g1.x, g1.y, g1.z, g1.w};
    float cc[8] = {c0.x, c0.y, c0.z, c0.w, c1.x, c1.y, c1.z, c1.w};
    u32 ow[4];
#pragma unroll
    for (int u = 0; u < 4; ++u) {
        float y0 = xs[2 * u] * rs * gg[2 * u] + cc[2 * u];
        float y1 = xs[2 * u + 1] * rs * gg[2 * u + 1] + cc[2 * u + 1];
        ow[u] = (u32)f2bf(y0) | ((u32)f2bf(y1) << 16);
    }
    *(uint4*)(fin + row * ND + lane * 8) = make_uint4(ow[0], ow[1], ow[2], ow[3]);
}

// ---------------- G kernel: Gm[b,c,t,s] = tril(Q_chunk @ K_chunk^T), bf16
__global__ __launch_bounds__(256) void gqk_kernel(
        const u16* __restrict__ Qb, const u16* __restrict__ Kb,
        u16* __restrict__ Gm) {
    __shared__ u16 Qs[64][520];
    __shared__ u16 Ks[64][520];
    int tid = threadIdx.x;
    int w = tid >> 6, lane = tid & 63;
    int b = blockIdx.x >> 5, c = blockIdx.x & 31;
    int t0 = c * CL;
    {
        int row = tid >> 2, cb = (tid & 3) * 128;
        const u16* qsrc = Qb + ((size_t)b * NS + t0 + row) * ND + cb;
        const u16* ksrc = Kb + ((size_t)b * NS + t0 + row) * ND + cb;
#pragma unroll
        for (int u = 0; u < 16; ++u) {
            *(short8*)&Qs[row][cb + u * 8] = *(const short8*)(qsrc + u * 8);
            *(short8*)&Ks[row][cb + u * 8] = *(const short8*)(ksrc + u * 8);
        }
    }
    __syncthreads();
    int qw = lane & 15, kg = lane >> 4;
    f32x4 ga[4];
#pragma unroll
    for (int ns = 0; ns < 4; ++ns) ga[ns] = (f32x4){0.f, 0.f, 0.f, 0.f};
    for (int kb = 0; kb < 16; ++kb) {
        short8 aq = *(const short8*)&Qs[(w << 4) + qw][kb * 32 + (kg << 3)];
#pragma unroll
        for (int ns = 0; ns < 4; ++ns) {
            short8 bk = *(const short8*)&Ks[(ns << 4) + qw][kb * 32 + (kg << 3)];
            ga[ns] = __builtin_amdgcn_mfma_f32_16x16x32_bf16(aq, bk, ga[ns], 0, 0, 0);
        }
    }
    u16* gout = Gm + (size_t)(b * NCH + c) * CL * CL;
#pragma unroll
    for (int ns = 0; ns < 4; ++ns) {
#pragma unroll
        for (int rg = 0; rg < 4; ++rg) {
            int t = (w << 4) + (kg << 2) + rg;
            int s = (ns << 4) + qw;
            gout[t * CL + s] = (s <= t) ? f2bf(ga[ns][rg]) : (u16)0;
        }
    }
}

// ---------------- chunked mLSTM recurrence. wg = (batch b, i-slice of 16).
__global__ __launch_bounds__(256) void recur_kernel(
        const u16* __restrict__ Qb, const u16* __restrict__ KT,
        const u16* __restrict__ Gm,
        const float* __restrict__ IT, const float* __restrict__ FT,
        const u16* __restrict__ VT, const u16* __restrict__ OT,
        float* __restrict__ H) {
    __shared__ u16 Chi[16][520];
    __shared__ u16 Clo[16][520];
    __shared__ u16 Ub[16][72];
    __shared__ float A1[64][21];
    __shared__ float A2[64][21];
    __shared__ float gam[16];
    __shared__ float mold[16];
    int tid = threadIdx.x;
    int w = tid >> 6, lane = tid & 63;
    int b = blockIdx.x >> 5;
    int i0 = (blockIdx.x & 31) << 4;
    int qw = lane & 15, kg = lane >> 4;
    if (tid < 16) mold[tid] = 0.f;
    f32x4 cacc[8];
#pragma unroll
    for (int n = 0; n < 8; ++n) cacc[n] = (f32x4){0.f, 0.f, 0.f, 0.f};
    __syncthreads();

    size_t bT = (size_t)b * NS;
    size_t bD = (size_t)b * ND;

    for (int c = 0; c < NCH; ++c) {
        int t0 = c * CL;
        // ---- phase 1: gate scan (4 i's per wave, lane = step)
        for (int r = 0; r < 4; ++r) {
            int il = (w << 2) + r;
            size_t gofs = (bD + i0 + il) * NS + t0 + lane;
            float ft = FT[gofs];
            float it = IT[gofs];
            float vv = bf2f(VT[gofs]);
            float bs = ft;
#pragma unroll
            for (int o = 1; o < 64; o <<= 1) {
                float nv = __shfl_up(bs, o);
                if (lane >= o) bs += nv;
            }
            float e = it - bs;
            float Mv = e;
#pragma unroll
            for (int o = 1; o < 64; o <<= 1) {
                float nv = __shfl_up(Mv, o);
                if (lane >= o) Mv = fmaxf(Mv, nv);
            }
            float mo = mold[il];
            Mv = fmaxf(Mv, mo);
            float E = __shfl(Mv, 63);
            Ub[il][lane] = f2bf(__expf(e - E) * vv);
            A1[lane][il] = __expf(mo - Mv);
            A2[lane][il] = __expf(fminf(E - Mv, 80.f));   // clamp: no inf
            if (lane == 63) {
                gam[il] = __expf(mo - E);
                mold[il] = bs + E;
            }
        }
        // ---- stage C_old to LDS as bf16 hi/lo
#pragma unroll
        for (int n = 0; n < 8; ++n) {
            int j = (w << 7) + (n << 4) + qw;
#pragma unroll
            for (int rg = 0; rg < 4; ++rg) {
                int irow = (kg << 2) + rg;
                float cv = cacc[n][rg];
                u16 hi = f2bf(cv);
                Chi[irow][j] = hi;
                Clo[irow][j] = f2bf(cv - bf2f(hi));
            }
        }
        __syncthreads();

        // ---- phase 2a: QC = Q @ C_old^T (hi + lo)
        f32x4 qch = (f32x4){0.f, 0.f, 0.f, 0.f};
        f32x4 qcl = (f32x4){0.f, 0.f, 0.f, 0.f};
        {
            const u16* qrow = Qb + (bT + t0 + (w << 4) + qw) * ND + (kg << 3);
#pragma unroll
            for (int kb = 0; kb < 16; ++kb) {
                short8 aq = *(const short8*)(qrow + kb * 32);
                short8 bh = *(const short8*)&Chi[qw][kb * 32 + (kg << 3)];
                short8 bl = *(const short8*)&Clo[qw][kb * 32 + (kg << 3)];
                qch = __builtin_amdgcn_mfma_f32_16x16x32_bf16(aq, bh, qch, 0, 0, 0);
                qcl = __builtin_amdgcn_mfma_f32_16x16x32_bf16(aq, bl, qcl, 0, 0, 0);
            }
        }
        // ---- phase 2b: intra = tril(G) @ U
        f32x4 pin = (f32x4){0.f, 0.f, 0.f, 0.f};
        {
            const u16* grow = Gm + ((size_t)(b * NCH + c) * CL + (w << 4) + qw) * CL + (kg << 3);
#pragma unroll
            for (int kb = 0; kb < 2; ++kb) {
                short8 ag = *(const short8*)(grow + kb * 32);
                short8 bu = *(const short8*)&Ub[qw][kb * 32 + (kg << 3)];
                pin = __builtin_amdgcn_mfma_f32_16x16x32_bf16(ag, bu, pin, 0, 0, 0);
            }
        }
        // ---- phase 2c: C = gamma*C + U^T @ K
        {
            float g[4];
#pragma unroll
            for (int rg = 0; rg < 4; ++rg) g[rg] = gam[(kg << 2) + rg];
#pragma unroll
            for (int n = 0; n < 8; ++n) {
#pragma unroll
                for (int rg = 0; rg < 4; ++rg) cacc[n][rg] *= g[rg];
            }
#pragma unroll
            for (int kb = 0; kb < 2; ++kb) {
                short8 au = *(const short8*)&Ub[qw][kb * 32 + (kg << 3)];
#pragma unroll
                for (int n = 0; n < 8; ++n) {
                    const u16* krow = KT + (bD + (w << 7) + (n << 4) + qw) * NS
                                      + t0 + kb * 32 + (kg << 3);
                    short8 bk = *(const short8*)krow;
                    cacc[n] = __builtin_amdgcn_mfma_f32_16x16x32_bf16(au, bk, cacc[n], 0, 0, 0);
                }
            }
        }
        // ---- phase 3: h = o * (A1*QC + A2*intra)
#pragma unroll
        for (int rg = 0; rg < 4; ++rg) {
            int tl = (w << 4) + (kg << 2) + rg;
            float o = bf2f(OT[(bD + i0 + qw) * NS + t0 + tl]);
            float h = o * (A1[tl][qw] * (qch[rg] + qcl[rg]) + A2[tl][qw] * pin[rg]);
            H[(bT + t0 + tl) * ND + i0 + qw] = h;
        }
        __syncthreads();
    }
}

// ---------------- bf16 MFMA GEMM, global_load_lds staging + XOR-swizzled LDS
// LDS linear [128][32] u16; position (r,s) holds global slot s^((r>>1)&3).
template <int MODE>
__global__ __launch_bounds__(256) void gemm_kernel(
        const u16* __restrict__ A, const u16* __restrict__ BT,
        int M, int N, int K, int lda, int ldb, int kwrap,
        const float* __restrict__ bias,
        char* __restrict__ pb,
        float* __restrict__ outf, u16* __restrict__ outh,
        const float* __restrict__ resid) {
    __shared__ u16 As[128 * 32];
    __shared__ u16 Bs[128 * 32];
    int tid = threadIdx.x;
    int wave = tid >> 6, lane = tid & 63;
    int wm = wave >> 1, wn = wave & 1;
    int m0 = blockIdx.y * 128;
    int n0 = blockIdx.x * 128;

    f32x4 acc[4][4];
#pragma unroll
    for (int fi = 0; fi < 4; ++fi)
#pragma unroll
        for (int fj = 0; fj < 4; ++fj)
            acc[fi][fj] = (f32x4){0.f, 0.f, 0.f, 0.f};

    // staging geometry: wave stages rows [wave*32, wave*32+32) of A and B,
    // two 16-row global_load_lds per matrix. lane -> (row = l>>2, slot = l&3),
    // global slot pre-swizzled: gs = slot ^ ((row>>1)&3).
    int srow = lane >> 2;
    int slot = lane & 3;
    int r0s = wave * 32 + srow;                 // q=0 row
    int gs0 = (slot ^ ((r0s >> 1) & 3)) << 3;   // elems
    int gs1 = (slot ^ (((r0s + 16) >> 1) & 3)) << 3;
    const u16* Ag0 = A + (size_t)(m0 + r0s) * lda + gs0;
    const u16* Ag1 = A + (size_t)(m0 + r0s + 16) * lda + gs1;
    const u16* Bg0 = BT + (size_t)(n0 + r0s) * ldb + gs0;
    const u16* Bg1 = BT + (size_t)(n0 + r0s + 16) * ldb + gs1;
    u16* Al0 = As + (size_t)(wave * 32) * 32;   // wave-uniform LDS bases
    u16* Al1 = As + (size_t)(wave * 32 + 16) * 32;
    u16* Bl0 = Bs + (size_t)(wave * 32) * 32;
    u16* Bl1 = Bs + (size_t)(wave * 32 + 16) * 32;

    // fragment read addresses (swizzled)
    int fr = lane & 15, kb = lane >> 4;
#pragma unroll 1
    for (int k0 = 0; k0 < K; k0 += 32) {
        int ak0 = k0 - (k0 >= kwrap ? kwrap : 0);
        __syncthreads();   // prior reads of LDS complete
        __builtin_amdgcn_global_load_lds((gas_u32*)(Ag0 + ak0), (las_u32*)Al0, 16, 0, 0);
        __builtin_amdgcn_global_load_lds((gas_u32*)(Ag1 + ak0), (las_u32*)Al1, 16, 0, 0);
        __builtin_amdgcn_global_load_lds((gas_u32*)(Bg0 + k0), (las_u32*)Bl0, 16, 0, 0);
        __builtin_amdgcn_global_load_lds((gas_u32*)(Bg1 + k0), (las_u32*)Bl1, 16, 0, 0);
        __syncthreads();   // drains vmcnt: staged data visible
        short8 fa[4], fb[4];
#pragma unroll
        for (int f = 0; f < 4; ++f) {
            int ra = wm * 64 + f * 16 + fr;
            fa[f] = *(const short8*)(As + ra * 32 + ((kb ^ ((ra >> 1) & 3)) << 3));
            int rb = wn * 64 + f * 16 + fr;
            fb[f] = *(const short8*)(Bs + rb * 32 + ((kb ^ ((rb >> 1) & 3)) << 3));
        }
#pragma unroll
        for (int fi = 0; fi < 4; ++fi)
#pragma unroll
            for (int fj = 0; fj < 4; ++fj)
                acc[fi][fj] = __builtin_amdgcn_mfma_f32_16x16x32_bf16(
                        fa[fi], fb[fj], acc[fi][fj], 0, 0, 0);
    }

    int rbase = (lane >> 4) * 4;
    int cbase = n0 + wn * 64 + (lane & 15);
#pragma unroll
    for (int fi = 0; fi < 4; ++fi) {
        int r0 = m0 + wm * 64 + fi * 16 + rbase;
#pragma unroll
        for (int fj = 0; fj < 4; ++fj) {
            int col = cbase + fj * 16;
            if (MODE == 0) {
                int p = col >> 9, d = col & 511;
                float bv_ = bias[col];
                float w0 = acc[fi][fj][0] + bv_;
                float w1 = acc[fi][fj][1] + bv_;
                float w2 = acc[fi][fj][2] + bv_;
                float w3 = acc[fi][fj][3] + bv_;
                size_t tb = ((size_t)(r0 >> 11) * ND + d) * NS + (r0 & 2047);
                if (p == 0) {
                    u16* q = (u16*)(pb + OFF_QB);
                    q[(size_t)(r0 + 0) * ND + d] = f2bf(w0);
                    q[(size_t)(r0 + 1) * ND + d] = f2bf(w1);
                    q[(size_t)(r0 + 2) * ND + d] = f2bf(w2);
                    q[(size_t)(r0 + 3) * ND + d] = f2bf(w3);
                } else if (p == 1) {
                    float s0 = w0 * KSCALE, s1 = w1 * KSCALE;
                    float s2 = w2 * KSCALE, s3 = w3 * KSCALE;
                    u16* kbuf = (u16*)(pb + OFF_KB);
                    kbuf[(size_t)(r0 + 0) * ND + d] = f2bf(s0);
                    kbuf[(size_t)(r0 + 1) * ND + d] = f2bf(s1);
                    kbuf[(size_t)(r0 + 2) * ND + d] = f2bf(s2);
                    kbuf[(size_t)(r0 + 3) * ND + d] = f2bf(s3);
                    uint2 wv = make_uint2((u32)f2bf(s0) | ((u32)f2bf(s1) << 16),
                                          (u32)f2bf(s2) | ((u32)f2bf(s3) << 16));
                    *(uint2*)((u16*)(pb + OFF_KT) + tb) = wv;
                } else if (p == 3) {
                    *(float4*)((float*)(pb + OFF_IT) + tb) = make_float4(w0, w1, w2, w3);
                } else if (p == 4) {
                    *(float4*)((float*)(pb + OFF_FT) + tb) = make_float4(w0, w1, w2, w3);
                } else if (p == 2) {
                    uint2 wv = make_uint2((u32)f2bf(w0) | ((u32)f2bf(w1) << 16),
                                          (u32)f2bf(w2) | ((u32)f2bf(w3) << 16));
                    *(uint2*)((u16*)(pb + OFF_VT) + tb) = wv;
                } else {
                    float s0 = 1.0f / (1.0f + __expf(-w0));
                    float s1 = 1.0f / (1.0f + __expf(-w1));
                    float s2 = 1.0f / (1.0f + __expf(-w2));
                    float s3 = 1.0f / (1.0f + __expf(-w3));
                    uint2 wv = make_uint2((u32)f2bf(s0) | ((u32)f2bf(s1) << 16),
                                          (u32)f2bf(s2) | ((u32)f2bf(s3) << 16));
                    *(uint2*)((u16*)(pb + OFF_OT) + tb) = wv;
                }
            } else {
#pragma unroll
                for (int r = 0; r < 4; ++r) {
                    int row = r0 + r;
                    float v = acc[fi][fj][r];
                    if (MODE == 1) {
                        float val = v + bias[col];
                        val = 0.5f * val * (1.0f + erff(val * 0.70710678118654752f));
                        outh[(size_t)row * N + col] = f2bf(val);
                    } else {
                        float val = v + bias[col] + resid[(size_t)row * ND + col];
                        outf[(size_t)row * ND + col] = val;
                    }
                }
            }
        }
    }
}

extern "C" void kernel_launch(void* const* d_in, const int* in_sizes, int n_in,
                              void* d_out, int out_size, void* d_ws, size_t ws_size,
                              hipStream_t stream) {
    const float* x    = (const float*)d_in[0];
    const float* ln1g = (const float*)d_in[1];
    const float* ln1b = (const float*)d_in[2];
    const float* ln2g = (const float*)d_in[3];
    const float* ln2b = (const float*)d_in[4];
    const float* Wq = (const float*)d_in[5];
    const float* bq = (const float*)d_in[6];
    const float* Wk = (const float*)d_in[7];
    const float* bk = (const float*)d_in[8];
    const float* Wv = (const float*)d_in[9];
    const float* bv = (const float*)d_in[10];
    const float* Wi = (const float*)d_in[11];
    const float* bi = (const float*)d_in[12];
    const float* Wf = (const float*)d_in[13];
    const float* bfp = (const float*)d_in[14];
    const float* Wo = (const float*)d_in[15];
    const float* bo = (const float*)d_in[16];
    const float* W1 = (const float*)d_in[17];
    const float* b1 = (const float*)d_in[18];
    const float* W2 = (const float*)d_in[19];
    const float* b2 = (const float*)d_in[20];
    float* out = (float*)d_out;

    char* ws = (char*)d_ws;
    size_t off = 0;
    u16* WcorrT = (u16*)(ws + off); off += (size_t)3072 * 1536 * 2;  // 9 MB
    u16* W1T    = (u16*)(ws + off); off += (size_t)2048 * 512 * 2;   // 2 MB
    u16* W2T    = (u16*)(ws + off); off += (size_t)512 * 2048 * 2;   // 2 MB
    float* ball = (float*)(ws + off); off += 3072 * 4;
    off = (off + 255) & ~(size_t)255;
    char* U = ws + off;
    u16*   Acorr = (u16*)(U + OFF_AC);
    float* Hbuf  = (float*)(U + OFF_AC);
    u16* ffnin = (u16*)U;                       // aliases dead Qbf
    u16* Gbuf  = (u16*)(U + OFF_KB);            // aliases dead Kbf/KT/VT/OT
    size_t needed = (size_t)(U - ws) + OFF_AC + (size_t)32 * 1024 * 1024;
    if (ws_size < needed) return;

    // 1. weights
    wcorr_kernel<<<(3072 * 1536) / 256, 256, 0, stream>>>(Wq, Wk, Wv, Wi, Wf, Wo, WcorrT);
    wconv_kernel<<<4096, 256, 0, stream>>>(W1, W1T, 9, 2048, 2048 * 512);
    wconv_kernel<<<4096, 256, 0, stream>>>(W2, W2T, 11, 512, 512 * 2048);
    bias_concat_kernel<<<12, 256, 0, stream>>>(bq, bk, bv, bi, bfp, bo, ball);

    // 2. LN1 -> [nH | nL]
    ln1_kernel<<<NM / 4, 256, 0, stream>>>(x, ln1g, ln1b, Acorr);

    // 3. fused split-precision proj GEMM: K=1536
    gemm_kernel<0><<<dim3(3072 / 128, NM / 128), 256, 0, stream>>>(
            Acorr, WcorrT, NM, 3072, 1536, 1024, 1536, 1024, ball,
            U, nullptr, nullptr, nullptr);

    // 4a. G = tril(Q K^T) per (batch, chunk)
    gqk_kernel<<<NB * NCH, 256, 0, stream>>>(
            (const u16*)(U + OFF_QB), (const u16*)(U + OFF_KB), (u16*)(U + OFF_G));

    // 4b. chunked recurrence
    recur_kernel<<<NB * 32, 256, 0, stream>>>(
            (const u16*)(U + OFF_QB), (const u16*)(U + OFF_KT), (const u16*)(U + OFF_G),
            (const float*)(U + OFF_IT), (const float*)(U + OFF_FT),
            (const u16*)(U + OFF_VT), (const u16*)(U + OFF_OT), Hbuf);

    // 5. residual + LN2
    resid_ln2_kernel<<<NM / 4, 256, 0, stream>>>(x, Hbuf, ln2g, ln2b, out, ffnin);

    // 6. FFN1
    gemm_kernel<1><<<dim3(2048 / 128, NM / 128), 256, 0, stream>>>(
            ffnin, W1T, NM, 2048, 512, 512, 512, 1 << 30, b1,
            nullptr, nullptr, Gbuf, nullptr);

    // 7. FFN2
    gemm_kernel<2><<<dim3(512 / 128, NM / 128), 256, 0, stream>>>(
            Gbuf, W2T, NM, 512, 2048, 2048, 2048, 1 << 30, b2,
            nullptr, out, nullptr, out);

    (void)in_sizes; (void)n_in; (void)out_size; (void)ws_size;
}

// Round 8
// 635.033 us; speedup vs baseline: 3.9014x; 1.1542x over previous
//
#include <hip/hip_runtime.h>
#include <hip/hip_bf16.h>
#include <cstdint>

typedef unsigned short u16;
typedef unsigned int u32;
typedef __attribute__((ext_vector_type(8))) short short8;
typedef __attribute__((ext_vector_type(4))) float f32x4;

#define NB 8
#define NS 2048
#define ND 512
#define NM (NB * NS)            // 16384 rows
#define CL 64                   // chunk length
#define NCH (NS / CL)           // 32 chunks
static constexpr size_t BSDn = (size_t)NM * ND;   // 8388608 elems
#define KSCALE 0.044194173824159216f              // 1/sqrt(512)

// U-region byte offsets
#define OFF_QB ((size_t)0)            // Qbf  [b,t,d] bf16 16MB
#define OFF_KB (BSDn * 2)             // Kbf  [b,t,d] bf16 (scaled) 16MB
#define OFF_KT (BSDn * 4)             // KT   [b,d,t] bf16 (scaled) 16MB
#define OFF_VT (BSDn * 6)             // VT   [b,d,t] bf16 16MB
#define OFF_OT (BSDn * 8)             // OT   [b,d,t] bf16 (sigmoid) 16MB
#define OFF_IT (BSDn * 10)            // IT   [b,d,t] f32 32MB
#define OFF_FT (BSDn * 14)            // FT   [b,d,t] f32 32MB
#define OFF_G  (BSDn * 18)            // Gm   [b][32][64][64] bf16 2MB
#define OFF_AC (BSDn * 18 + ((size_t)2 << 20))   // Acorr (32MB) / Hbuf alias

typedef __attribute__((address_space(1))) const u32 gas_u32;
typedef __attribute__((address_space(3))) u32 las_u32;

__device__ __forceinline__ u16 f2bf(float f) {
    u32 i = __builtin_bit_cast(u32, f);
    u32 r = i + 0x7FFFu + ((i >> 16) & 1u);
    return (u16)(r >> 16);
}
__device__ __forceinline__ float bf2f(u16 h) {
    return __builtin_bit_cast(float, (u32)h << 16);
}

// ---------------- split-precision weight build for it,ft: [1024][1536] = [WH|WH|WL]
__global__ __launch_bounds__(256) void wcorr_kernel(
        const float* __restrict__ Wi, const float* __restrict__ Wf,
        u16* __restrict__ WT) {
    int idx = blockIdx.x * 256 + threadIdx.x;   // 1024*1536
    int n = idx / 1536, k = idx - n * 1536;
    const float* Wp = (n >> 9) ? Wf : Wi;
    int d = n & 511;
    u16 o;
    if (k < 1024) {
        o = f2bf(Wp[(size_t)(k & 511) * 512 + d]);
    } else {
        float w = Wp[(size_t)(k - 1024) * 512 + d];
        o = f2bf(w - bf2f(f2bf(w)));
    }
    WT[idx] = o;
}

__global__ __launch_bounds__(256) void wconv_kernel(const float* __restrict__ W,
        u16* __restrict__ WT, int lk, int N, int total) {
    int idx = blockIdx.x * 256 + threadIdx.x;
    if (idx >= total) return;
    int n = idx >> lk;
    int k = idx & ((1 << lk) - 1);
    WT[idx] = f2bf(W[(size_t)k * N + n]);
}

// ---------------- concat biases: [q,k,v,o | it,ft] = 3072
__global__ __launch_bounds__(256) void bias_concat_kernel(
        const float* b0, const float* b1, const float* b2,
        const float* b3, const float* b4, const float* b5,
        float* __restrict__ ball) {
    int idx = blockIdx.x * 256 + threadIdx.x;
    if (idx >= 3072) return;
    int p = idx >> 9, d = idx & 511;
    float v;
    switch (p) {
        case 0: v = b0[d]; break;   // bq
        case 1: v = b1[d]; break;   // bk
        case 2: v = b2[d]; break;   // bv
        case 3: v = b3[d]; break;   // bo
        case 4: v = b4[d]; break;   // bi
        default: v = b5[d]; break;  // bf
    }
    ball[idx] = v;
}

// ---------------- LN1: x -> Acorr [16384][1024] = [nH | nL]
__global__ __launch_bounds__(256) void ln1_kernel(const float* __restrict__ x,
        const float* __restrict__ g, const float* __restrict__ bb,
        u16* __restrict__ nout) {
    int wave = threadIdx.x >> 6, lane = threadIdx.x & 63;
    size_t row = (size_t)blockIdx.x * 4 + wave;
    const float* xr = x + row * ND + lane * 8;
    float4 a0 = *(const float4*)xr;
    float4 a1 = *(const float4*)(xr + 4);
    float xs[8] = {a0.x, a0.y, a0.z, a0.w, a1.x, a1.y, a1.z, a1.w};
    float s = 0.f;
#pragma unroll
    for (int u = 0; u < 8; ++u) s += xs[u];
#pragma unroll
    for (int off = 32; off; off >>= 1) s += __shfl_xor(s, off);
    float mu = s * (1.0f / ND);
    float ss = 0.f;
#pragma unroll
    for (int u = 0; u < 8; ++u) { xs[u] -= mu; ss += xs[u] * xs[u]; }
#pragma unroll
    for (int off = 32; off; off >>= 1) ss += __shfl_xor(ss, off);
    float rs = rsqrtf(ss * (1.0f / ND) + 1e-5f);
    const float* gp = g + lane * 8;
    const float* bp = bb + lane * 8;
    float4 g0 = *(const float4*)gp, g1 = *(const float4*)(gp + 4);
    float4 c0 = *(const float4*)bp, c1 = *(const float4*)(bp + 4);
    float gg[8] = {g0.x, g0.y, g0.z, g0.w, g1.x, g1.y, g1.z, g1.w};
    float cc[8] = {c0.x, c0.y, c0.z, c0.w, c1.x, c1.y, c1.z, c1.w};
    u32 owh[4], owl[4];
#pragma unroll
    for (int u = 0; u < 4; ++u) {
        float y0 = xs[2 * u] * rs * gg[2 * u] + cc[2 * u];
        float y1 = xs[2 * u + 1] * rs * gg[2 * u + 1] + cc[2 * u + 1];
        u16 h0 = f2bf(y0), h1 = f2bf(y1);
        u16 l0 = f2bf(y0 - bf2f(h0)), l1 = f2bf(y1 - bf2f(h1));
        owh[u] = (u32)h0 | ((u32)h1 << 16);
        owl[u] = (u32)l0 | ((u32)l1 << 16);
    }
    u16* rb = nout + row * 1024;
    *(uint4*)(rb + lane * 8) = make_uint4(owh[0], owh[1], owh[2], owh[3]);
    *(uint4*)(rb + 512 + lane * 8) = make_uint4(owl[0], owl[1], owl[2], owl[3]);
}

// ---------------- residual add + LN2
__global__ __launch_bounds__(256) void resid_ln2_kernel(const float* __restrict__ x,
        const float* __restrict__ h, const float* __restrict__ g,
        const float* __restrict__ bb, float* __restrict__ outb,
        u16* __restrict__ fin) {
    int wave = threadIdx.x >> 6, lane = threadIdx.x & 63;
    size_t row = (size_t)blockIdx.x * 4 + wave;
    const float* xr = x + row * ND + lane * 8;
    const float* hr = h + row * ND + lane * 8;
    float4 a0 = *(const float4*)xr;
    float4 a1 = *(const float4*)(xr + 4);
    float4 h0 = *(const float4*)hr;
    float4 h1 = *(const float4*)(hr + 4);
    float xs[8] = {a0.x + h0.x, a0.y + h0.y, a0.z + h0.z, a0.w + h0.w,
                   a1.x + h1.x, a1.y + h1.y, a1.z + h1.z, a1.w + h1.w};
    float* orow = outb + row * ND + lane * 8;
    *(float4*)orow = make_float4(xs[0], xs[1], xs[2], xs[3]);
    *(float4*)(orow + 4) = make_float4(xs[4], xs[5], xs[6], xs[7]);
    float s = 0.f;
#pragma unroll
    for (int u = 0; u < 8; ++u) s += xs[u];
#pragma unroll
    for (int off = 32; off; off >>= 1) s += __shfl_xor(s, off);
    float mu = s * (1.0f / ND);
    float ss = 0.f;
#pragma unroll
    for (int u = 0; u < 8; ++u) { xs[u] -= mu; ss += xs[u] * xs[u]; }
#pragma unroll
    for (int off = 32; off; off >>= 1) ss += __shfl_xor(ss, off);
    float rs = rsqrtf(ss * (1.0f / ND) + 1e-5f);
    const float* gp = g + lane * 8;
    const float* bp = bb + lane * 8;
    float4 g0 = *(const float4*)gp, g1 = *(const float4*)(gp + 4);
    float4 c0 = *(const float4*)bp, c1 = *(const float4*)(bp + 4);
    float gg[8] = {g0.x, g0.y, g0.z, g0.w, g1.x, g1.y, g1.z, g1.w};
    float cc[8] = {c0.x, c0.y, c0.z, c0.w, c1.x, c1.y, c1.z, c1.w};
    u32 ow[4];
#pragma unroll
    for (int u = 0; u < 4; ++u) {
        float y0 = xs[2 * u] * rs * gg[2 * u] + cc[2 * u];
        float y1 = xs[2 * u + 1] * rs * gg[2 * u + 1] + cc[2 * u + 1];
        ow[u] = (u32)f2bf(y0) | ((u32)f2bf(y1) << 16);
    }
    *(uint4*)(fin + row * ND + lane * 8) = make_uint4(ow[0], ow[1], ow[2], ow[3]);
}

// ---------------- G kernel: Gm[b,c,t,s] = tril(Q_chunk @ K_chunk^T), bf16
__global__ __launch_bounds__(256) void gqk_kernel(
        const u16* __restrict__ Qb, const u16* __restrict__ Kb,
        u16* __restrict__ Gm) {
    __shared__ u16 Qs[64][520];
    __shared__ u16 Ks[64][520];
    int tid = threadIdx.x;
    int w = tid >> 6, lane = tid & 63;
    int b = blockIdx.x >> 5, c = blockIdx.x & 31;
    int t0 = c * CL;
    {
        int row = tid >> 2, cb = (tid & 3) * 128;
        const u16* qsrc = Qb + ((size_t)b * NS + t0 + row) * ND + cb;
        const u16* ksrc = Kb + ((size_t)b * NS + t0 + row) * ND + cb;
#pragma unroll
        for (int u = 0; u < 16; ++u) {
            *(short8*)&Qs[row][cb + u * 8] = *(const short8*)(qsrc + u * 8);
            *(short8*)&Ks[row][cb + u * 8] = *(const short8*)(ksrc + u * 8);
        }
    }
    __syncthreads();
    int qw = lane & 15, kg = lane >> 4;
    f32x4 ga[4];
#pragma unroll
    for (int ns = 0; ns < 4; ++ns) ga[ns] = (f32x4){0.f, 0.f, 0.f, 0.f};
    for (int kb = 0; kb < 16; ++kb) {
        short8 aq = *(const short8*)&Qs[(w << 4) + qw][kb * 32 + (kg << 3)];
#pragma unroll
        for (int ns = 0; ns < 4; ++ns) {
            short8 bk = *(const short8*)&Ks[(ns << 4) + qw][kb * 32 + (kg << 3)];
            ga[ns] = __builtin_amdgcn_mfma_f32_16x16x32_bf16(aq, bk, ga[ns], 0, 0, 0);
        }
    }
    u16* gout = Gm + (size_t)(b * NCH + c) * CL * CL;
#pragma unroll
    for (int ns = 0; ns < 4; ++ns) {
#pragma unroll
        for (int rg = 0; rg < 4; ++rg) {
            int t = (w << 4) + (kg << 2) + rg;
            int s = (ns << 4) + qw;
            gout[t * CL + s] = (s <= t) ? f2bf(ga[ns][rg]) : (u16)0;
        }
    }
}

// ---------------- chunked mLSTM recurrence. wg = (batch b, i-slice of 16).
__global__ __launch_bounds__(256) void recur_kernel(
        const u16* __restrict__ Qb, const u16* __restrict__ KT,
        const u16* __restrict__ Gm,
        const float* __restrict__ IT, const float* __restrict__ FT,
        const u16* __restrict__ VT, const u16* __restrict__ OT,
        float* __restrict__ H) {
    __shared__ u16 Chi[16][520];
    __shared__ u16 Clo[16][520];
    __shared__ u16 Ub[16][72];
    __shared__ float A1[64][21];
    __shared__ float A2[64][21];
    __shared__ float gam[16];
    __shared__ float mold[16];
    int tid = threadIdx.x;
    int w = tid >> 6, lane = tid & 63;
    int b = blockIdx.x >> 5;
    int i0 = (blockIdx.x & 31) << 4;
    int qw = lane & 15, kg = lane >> 4;
    if (tid < 16) mold[tid] = 0.f;
    f32x4 cacc[8];
#pragma unroll
    for (int n = 0; n < 8; ++n) cacc[n] = (f32x4){0.f, 0.f, 0.f, 0.f};
    __syncthreads();

    size_t bT = (size_t)b * NS;
    size_t bD = (size_t)b * ND;

    for (int c = 0; c < NCH; ++c) {
        int t0 = c * CL;
        // ---- phase 1: gate scan (4 i's per wave, lane = step)
        for (int r = 0; r < 4; ++r) {
            int il = (w << 2) + r;
            size_t gofs = (bD + i0 + il) * NS + t0 + lane;
            float ft = FT[gofs];
            float it = IT[gofs];
            float vv = bf2f(VT[gofs]);
            float bs = ft;
#pragma unroll
            for (int o = 1; o < 64; o <<= 1) {
                float nv = __shfl_up(bs, o);
                if (lane >= o) bs += nv;
            }
            float e = it - bs;
            float Mv = e;
#pragma unroll
            for (int o = 1; o < 64; o <<= 1) {
                float nv = __shfl_up(Mv, o);
                if (lane >= o) Mv = fmaxf(Mv, nv);
            }
            float mo = mold[il];
            Mv = fmaxf(Mv, mo);
            float E = __shfl(Mv, 63);
            Ub[il][lane] = f2bf(__expf(e - E) * vv);
            A1[lane][il] = __expf(mo - Mv);
            A2[lane][il] = __expf(fminf(E - Mv, 80.f));   // clamp: no inf
            if (lane == 63) {
                gam[il] = __expf(mo - E);
                mold[il] = bs + E;
            }
        }
        // ---- stage C_old to LDS as bf16 hi/lo
#pragma unroll
        for (int n = 0; n < 8; ++n) {
            int j = (w << 7) + (n << 4) + qw;
#pragma unroll
            for (int rg = 0; rg < 4; ++rg) {
                int irow = (kg << 2) + rg;
                float cv = cacc[n][rg];
                u16 hi = f2bf(cv);
                Chi[irow][j] = hi;
                Clo[irow][j] = f2bf(cv - bf2f(hi));
            }
        }
        __syncthreads();

        // ---- phase 2a: QC = Q @ C_old^T (hi + lo)
        f32x4 qch = (f32x4){0.f, 0.f, 0.f, 0.f};
        f32x4 qcl = (f32x4){0.f, 0.f, 0.f, 0.f};
        {
            const u16* qrow = Qb + (bT + t0 + (w << 4) + qw) * ND + (kg << 3);
#pragma unroll
            for (int kb = 0; kb < 16; ++kb) {
                short8 aq = *(const short8*)(qrow + kb * 32);
                short8 bh = *(const short8*)&Chi[qw][kb * 32 + (kg << 3)];
                short8 bl = *(const short8*)&Clo[qw][kb * 32 + (kg << 3)];
                qch = __builtin_amdgcn_mfma_f32_16x16x32_bf16(aq, bh, qch, 0, 0, 0);
                qcl = __builtin_amdgcn_mfma_f32_16x16x32_bf16(aq, bl, qcl, 0, 0, 0);
            }
        }
        // ---- phase 2b: intra = tril(G) @ U
        f32x4 pin = (f32x4){0.f, 0.f, 0.f, 0.f};
        {
            const u16* grow = Gm + ((size_t)(b * NCH + c) * CL + (w << 4) + qw) * CL + (kg << 3);
#pragma unroll
            for (int kb = 0; kb < 2; ++kb) {
                short8 ag = *(const short8*)(grow + kb * 32);
                short8 bu = *(const short8*)&Ub[qw][kb * 32 + (kg << 3)];
                pin = __builtin_amdgcn_mfma_f32_16x16x32_bf16(ag, bu, pin, 0, 0, 0);
            }
        }
        // ---- phase 2c: C = gamma*C + U^T @ K
        {
            float g[4];
#pragma unroll
            for (int rg = 0; rg < 4; ++rg) g[rg] = gam[(kg << 2) + rg];
#pragma unroll
            for (int n = 0; n < 8; ++n) {
#pragma unroll
                for (int rg = 0; rg < 4; ++rg) cacc[n][rg] *= g[rg];
            }
#pragma unroll
            for (int kb = 0; kb < 2; ++kb) {
                short8 au = *(const short8*)&Ub[qw][kb * 32 + (kg << 3)];
#pragma unroll
                for (int n = 0; n < 8; ++n) {
                    const u16* krow = KT + (bD + (w << 7) + (n << 4) + qw) * NS
                                      + t0 + kb * 32 + (kg << 3);
                    short8 bk = *(const short8*)krow;
                    cacc[n] = __builtin_amdgcn_mfma_f32_16x16x32_bf16(au, bk, cacc[n], 0, 0, 0);
                }
            }
        }
        // ---- phase 3: h = o * (A1*QC + A2*intra)
#pragma unroll
        for (int rg = 0; rg < 4; ++rg) {
            int tl = (w << 4) + (kg << 2) + rg;
            float o = bf2f(OT[(bD + i0 + qw) * NS + t0 + tl]);
            float h = o * (A1[tl][qw] * (qch[rg] + qcl[rg]) + A2[tl][qw] * pin[rg]);
            H[(bT + t0 + tl) * ND + i0 + qw] = h;
        }
        __syncthreads();
    }
}

// ---------------- bf16 MFMA GEMM, global_load_lds + XOR swizzle + LDS double-buffer
// MODE 0: qkvo (N=2048) -> QB,KB+KT,VT,OT   MODE 3: itft (N=1024) -> IT,FT
// MODE 1: ffn1 gelu bf16                    MODE 2: ffn2 + resid f32
template <int MODE>
__global__ __launch_bounds__(256) void gemm_kernel(
        const u16* __restrict__ A, const u16* __restrict__ BT,
        int M, int N, int K, int lda, int ldb, int kwrap,
        const float* __restrict__ bias,
        char* __restrict__ pb,
        float* __restrict__ outf, u16* __restrict__ outh,
        const float* __restrict__ resid) {
    __shared__ u16 As[2][128 * 32];
    __shared__ u16 Bs[2][128 * 32];
    int tid = threadIdx.x;
    int wave = tid >> 6, lane = tid & 63;
    int wm = wave >> 1, wn = wave & 1;
    int m0 = blockIdx.y * 128;
    int n0 = blockIdx.x * 128;

    f32x4 acc[4][4];
#pragma unroll
    for (int fi = 0; fi < 4; ++fi)
#pragma unroll
        for (int fj = 0; fj < 4; ++fj)
            acc[fi][fj] = (f32x4){0.f, 0.f, 0.f, 0.f};

    // staging: wave stages rows [wave*32, +32); lane -> (row=l>>2, slot=l&3),
    // global slot pre-swizzled gs = slot ^ ((row>>1)&3)  (LDS stays linear)
    int srow = lane >> 2;
    int slot = lane & 3;
    int r0s = wave * 32 + srow;
    int gs0 = (slot ^ ((r0s >> 1) & 3)) << 3;
    int gs1 = (slot ^ (((r0s + 16) >> 1) & 3)) << 3;
    const u16* Ag0 = A + (size_t)(m0 + r0s) * lda + gs0;
    const u16* Ag1 = A + (size_t)(m0 + r0s + 16) * lda + gs1;
    const u16* Bg0 = BT + (size_t)(n0 + r0s) * ldb + gs0;
    const u16* Bg1 = BT + (size_t)(n0 + r0s + 16) * ldb + gs1;
    int wl0 = wave * 32 * 32;          // wave-uniform LDS elem offsets
    int wl1 = wl0 + 16 * 32;

    int fr = lane & 15, kb = lane >> 4;
    int ra[4], rb4[4], sa[4], sb[4];
#pragma unroll
    for (int f = 0; f < 4; ++f) {
        ra[f] = wm * 64 + f * 16 + fr;
        rb4[f] = wn * 64 + f * 16 + fr;
        sa[f] = ra[f] * 32 + ((kb ^ ((ra[f] >> 1) & 3)) << 3);
        sb[f] = rb4[f] * 32 + ((kb ^ ((rb4[f] >> 1) & 3)) << 3);
    }

    int nk = K >> 5;
    // prologue: stage tile 0 into buffer 0
    __builtin_amdgcn_global_load_lds((gas_u32*)Ag0, (las_u32*)(&As[0][wl0]), 16, 0, 0);
    __builtin_amdgcn_global_load_lds((gas_u32*)Ag1, (las_u32*)(&As[0][wl1]), 16, 0, 0);
    __builtin_amdgcn_global_load_lds((gas_u32*)Bg0, (las_u32*)(&Bs[0][wl0]), 16, 0, 0);
    __builtin_amdgcn_global_load_lds((gas_u32*)Bg1, (las_u32*)(&Bs[0][wl1]), 16, 0, 0);
    __syncthreads();
#pragma unroll 2
    for (int t = 0; t < nk; ++t) {
        int cur = t & 1;
        if (t + 1 < nk) {                     // prefetch tile t+1 into buf^1
            int k0 = (t + 1) << 5;
            int ak0 = k0 - (k0 >= kwrap ? kwrap : 0);
            __builtin_amdgcn_global_load_lds((gas_u32*)(Ag0 + ak0), (las_u32*)(&As[cur ^ 1][wl0]), 16, 0, 0);
            __builtin_amdgcn_global_load_lds((gas_u32*)(Ag1 + ak0), (las_u32*)(&As[cur ^ 1][wl1]), 16, 0, 0);
            __builtin_amdgcn_global_load_lds((gas_u32*)(Bg0 + k0), (las_u32*)(&Bs[cur ^ 1][wl0]), 16, 0, 0);
            __builtin_amdgcn_global_load_lds((gas_u32*)(Bg1 + k0), (las_u32*)(&Bs[cur ^ 1][wl1]), 16, 0, 0);
        }
        short8 fa[4], fb[4];
#pragma unroll
        for (int f = 0; f < 4; ++f) {
            fa[f] = *(const short8*)(&As[cur][sa[f]]);
            fb[f] = *(const short8*)(&Bs[cur][sb[f]]);
        }
#pragma unroll
        for (int fi = 0; fi < 4; ++fi)
#pragma unroll
            for (int fj = 0; fj < 4; ++fj)
                acc[fi][fj] = __builtin_amdgcn_mfma_f32_16x16x32_bf16(
                        fa[fi], fb[fj], acc[fi][fj], 0, 0, 0);
        __syncthreads();   // drains prefetch (vmcnt0) + all reads of buf[cur] done
    }

    int rbase = (lane >> 4) * 4;
    int cbase = n0 + wn * 64 + (lane & 15);
#pragma unroll
    for (int fi = 0; fi < 4; ++fi) {
        int r0 = m0 + wm * 64 + fi * 16 + rbase;
#pragma unroll
        for (int fj = 0; fj < 4; ++fj) {
            int col = cbase + fj * 16;
            if (MODE == 0) {
                int p = col >> 9, d = col & 511;
                float bv_ = bias[col];
                float w0 = acc[fi][fj][0] + bv_;
                float w1 = acc[fi][fj][1] + bv_;
                float w2 = acc[fi][fj][2] + bv_;
                float w3 = acc[fi][fj][3] + bv_;
                size_t tb = ((size_t)(r0 >> 11) * ND + d) * NS + (r0 & 2047);
                if (p == 0) {                  // q
                    u16* q = (u16*)(pb + OFF_QB);
                    q[(size_t)(r0 + 0) * ND + d] = f2bf(w0);
                    q[(size_t)(r0 + 1) * ND + d] = f2bf(w1);
                    q[(size_t)(r0 + 2) * ND + d] = f2bf(w2);
                    q[(size_t)(r0 + 3) * ND + d] = f2bf(w3);
                } else if (p == 1) {           // k scaled: row-major + transposed
                    float s0 = w0 * KSCALE, s1 = w1 * KSCALE;
                    float s2 = w2 * KSCALE, s3 = w3 * KSCALE;
                    u16* kbuf = (u16*)(pb + OFF_KB);
                    kbuf[(size_t)(r0 + 0) * ND + d] = f2bf(s0);
                    kbuf[(size_t)(r0 + 1) * ND + d] = f2bf(s1);
                    kbuf[(size_t)(r0 + 2) * ND + d] = f2bf(s2);
                    kbuf[(size_t)(r0 + 3) * ND + d] = f2bf(s3);
                    uint2 wv = make_uint2((u32)f2bf(s0) | ((u32)f2bf(s1) << 16),
                                          (u32)f2bf(s2) | ((u32)f2bf(s3) << 16));
                    *(uint2*)((u16*)(pb + OFF_KT) + tb) = wv;
                } else if (p == 2) {           // v
                    uint2 wv = make_uint2((u32)f2bf(w0) | ((u32)f2bf(w1) << 16),
                                          (u32)f2bf(w2) | ((u32)f2bf(w3) << 16));
                    *(uint2*)((u16*)(pb + OFF_VT) + tb) = wv;
                } else {                       // o: sigmoid
                    float s0 = 1.0f / (1.0f + __expf(-w0));
                    float s1 = 1.0f / (1.0f + __expf(-w1));
                    float s2 = 1.0f / (1.0f + __expf(-w2));
                    float s3 = 1.0f / (1.0f + __expf(-w3));
                    uint2 wv = make_uint2((u32)f2bf(s0) | ((u32)f2bf(s1) << 16),
                                          (u32)f2bf(s2) | ((u32)f2bf(s3) << 16));
                    *(uint2*)((u16*)(pb + OFF_OT) + tb) = wv;
                }
            } else if (MODE == 3) {
                int p = col >> 9, d = col & 511;
                float bv_ = bias[col];
                float w0 = acc[fi][fj][0] + bv_;
                float w1 = acc[fi][fj][1] + bv_;
                float w2 = acc[fi][fj][2] + bv_;
                float w3 = acc[fi][fj][3] + bv_;
                size_t tb = ((size_t)(r0 >> 11) * ND + d) * NS + (r0 & 2047);
                float* dst = (float*)(pb + (p == 0 ? OFF_IT : OFF_FT));
                *(float4*)(dst + tb) = make_float4(w0, w1, w2, w3);
            } else {
#pragma unroll
                for (int r = 0; r < 4; ++r) {
                    int row = r0 + r;
                    float v = acc[fi][fj][r];
                    if (MODE == 1) {
                        float val = v + bias[col];
                        val = 0.5f * val * (1.0f + erff(val * 0.70710678118654752f));
                        outh[(size_t)row * N + col] = f2bf(val);
                    } else {
                        float val = v + bias[col] + resid[(size_t)row * ND + col];
                        outf[(size_t)row * ND + col] = val;
                    }
                }
            }
        }
    }
}

extern "C" void kernel_launch(void* const* d_in, const int* in_sizes, int n_in,
                              void* d_out, int out_size, void* d_ws, size_t ws_size,
                              hipStream_t stream) {
    const float* x    = (const float*)d_in[0];
    const float* ln1g = (const float*)d_in[1];
    const float* ln1b = (const float*)d_in[2];
    const float* ln2g = (const float*)d_in[3];
    const float* ln2b = (const float*)d_in[4];
    const float* Wq = (const float*)d_in[5];
    const float* bq = (const float*)d_in[6];
    const float* Wk = (const float*)d_in[7];
    const float* bk = (const float*)d_in[8];
    const float* Wv = (const float*)d_in[9];
    const float* bv = (const float*)d_in[10];
    const float* Wi = (const float*)d_in[11];
    const float* bi = (const float*)d_in[12];
    const float* Wf = (const float*)d_in[13];
    const float* bfp = (const float*)d_in[14];
    const float* Wo = (const float*)d_in[15];
    const float* bo = (const float*)d_in[16];
    const float* W1 = (const float*)d_in[17];
    const float* b1 = (const float*)d_in[18];
    const float* W2 = (const float*)d_in[19];
    const float* b2 = (const float*)d_in[20];
    float* out = (float*)d_out;

    char* ws = (char*)d_ws;
    size_t off = 0;
    u16* W4T    = (u16*)(ws + off); off += (size_t)2048 * 512 * 2;   // 2 MB  [q,k,v,o]
    u16* WcT    = (u16*)(ws + off); off += (size_t)1024 * 1536 * 2;  // 3 MB  [it,ft]
    u16* W1T    = (u16*)(ws + off); off += (size_t)2048 * 512 * 2;   // 2 MB
    u16* W2T    = (u16*)(ws + off); off += (size_t)512 * 2048 * 2;   // 2 MB
    float* ball = (float*)(ws + off); off += 3072 * 4;
    off = (off + 255) & ~(size_t)255;
    char* U = ws + off;
    u16*   Acorr = (u16*)(U + OFF_AC);
    float* Hbuf  = (float*)(U + OFF_AC);
    u16* ffnin = (u16*)U;                       // aliases dead Qbf
    u16* Gbuf  = (u16*)(U + OFF_KB);            // aliases dead Kbf/KT/VT/OT
    size_t needed = (size_t)(U - ws) + OFF_AC + (size_t)32 * 1024 * 1024;
    if (ws_size < needed) return;

    // 1. weights
    wconv_kernel<<<1024, 256, 0, stream>>>(Wq, W4T, 9, 512, 512 * 512);
    wconv_kernel<<<1024, 256, 0, stream>>>(Wk, W4T + (size_t)512 * 512, 9, 512, 512 * 512);
    wconv_kernel<<<1024, 256, 0, stream>>>(Wv, W4T + (size_t)2 * 512 * 512, 9, 512, 512 * 512);
    wconv_kernel<<<1024, 256, 0, stream>>>(Wo, W4T + (size_t)3 * 512 * 512, 9, 512, 512 * 512);
    wcorr_kernel<<<(1024 * 1536) / 256, 256, 0, stream>>>(Wi, Wf, WcT);
    wconv_kernel<<<4096, 256, 0, stream>>>(W1, W1T, 9, 2048, 2048 * 512);
    wconv_kernel<<<4096, 256, 0, stream>>>(W2, W2T, 11, 512, 512 * 2048);
    bias_concat_kernel<<<12, 256, 0, stream>>>(bq, bk, bv, bo, bi, bfp, ball);

    // 2. LN1 -> [nH | nL]
    ln1_kernel<<<NM / 4, 256, 0, stream>>>(x, ln1g, ln1b, Acorr);

    // 3a. qkvo GEMM: K=512 (nH @ WH)
    gemm_kernel<0><<<dim3(2048 / 128, NM / 128), 256, 0, stream>>>(
            Acorr, W4T, NM, 2048, 512, 1024, 512, 1 << 30, ball,
            U, nullptr, nullptr, nullptr);
    // 3b. it/ft split-precision GEMM: K=1536, A wraps at 1024
    gemm_kernel<3><<<dim3(1024 / 128, NM / 128), 256, 0, stream>>>(
            Acorr, WcT, NM, 1024, 1536, 1024, 1536, 1024, ball + 2048,
            U, nullptr, nullptr, nullptr);

    // 4a. G = tril(Q K^T) per (batch, chunk)
    gqk_kernel<<<NB * NCH, 256, 0, stream>>>(
            (const u16*)(U + OFF_QB), (const u16*)(U + OFF_KB), (u16*)(U + OFF_G));

    // 4b. chunked recurrence
    recur_kernel<<<NB * 32, 256, 0, stream>>>(
            (const u16*)(U + OFF_QB), (const u16*)(U + OFF_KT), (const u16*)(U + OFF_G),
            (const float*)(U + OFF_IT), (const float*)(U + OFF_FT),
            (const u16*)(U + OFF_VT), (const u16*)(U + OFF_OT), Hbuf);

    // 5. residual + LN2
    resid_ln2_kernel<<<NM / 4, 256, 0, stream>>>(x, Hbuf, ln2g, ln2b, out, ffnin);

    // 6. FFN1
    gemm_kernel<1><<<dim3(2048 / 128, NM / 128), 256, 0, stream>>>(
            ffnin, W1T, NM, 2048, 512, 512, 512, 1 << 30, b1,
            nullptr, nullptr, Gbuf, nullptr);

    // 7. FFN2
    gemm_kernel<2><<<dim3(512 / 128, NM / 128), 256, 0, stream>>>(
            Gbuf, W2T, NM, 512, 2048, 2048, 2048, 1 << 30, b2,
            nullptr, out, nullptr, out);

    (void)in_sizes; (void)n_in; (void)out_size; (void)ws_size;
}

// Round 9
// 583.996 us; speedup vs baseline: 4.2424x; 1.0874x over previous
//
#include <hip/hip_runtime.h>
#include <hip/hip_bf16.h>
#include <cstdint>

typedef unsigned short u16;
typedef unsigned int u32;
typedef __attribute__((ext_vector_type(8))) short short8;
typedef __attribute__((ext_vector_type(4))) float f32x4;

#define NB 8
#define NS 2048
#define ND 512
#define NM (NB * NS)            // 16384 rows
#define CL 64                   // chunk length
#define NCH (NS / CL)           // 32 chunks
static constexpr size_t BSDn = (size_t)NM * ND;   // 8388608 elems
#define KSCALE 0.044194173824159216f              // 1/sqrt(512)

// U-region byte offsets
#define OFF_QB ((size_t)0)            // Qbf  [b,t,d] bf16 16MB
#define OFF_KB (BSDn * 2)             // Kbf  [b,t,d] bf16 (scaled) 16MB
#define OFF_KT (BSDn * 4)             // KT   [b,d,t] bf16 (scaled) 16MB
#define OFF_VT (BSDn * 6)             // VT   [b,d,t] bf16 16MB
#define OFF_OT (BSDn * 8)             // OT   [b,d,t] bf16 (sigmoid) 16MB
#define OFF_IT (BSDn * 10)            // IT   [b,d,t] f32 32MB
#define OFF_FT (BSDn * 14)            // FT   [b,d,t] f32 32MB
#define OFF_G  (BSDn * 18)            // Gm   [b][32][64][64] bf16 2MB
#define OFF_AC (BSDn * 18 + ((size_t)2 << 20))   // Acorr (32MB) / Hbuf alias

typedef __attribute__((address_space(1))) const u32 gas_u32;
typedef __attribute__((address_space(3))) u32 las_u32;

__device__ __forceinline__ u16 f2bf(float f) {
    u32 i = __builtin_bit_cast(u32, f);
    u32 r = i + 0x7FFFu + ((i >> 16) & 1u);
    return (u16)(r >> 16);
}
__device__ __forceinline__ float bf2f(u16 h) {
    return __builtin_bit_cast(float, (u32)h << 16);
}

// ---------------- split-precision weight build for it,ft: [1024][1536] = [WH|WH|WL]
__global__ __launch_bounds__(256) void wcorr_kernel(
        const float* __restrict__ Wi, const float* __restrict__ Wf,
        u16* __restrict__ WT) {
    int idx = blockIdx.x * 256 + threadIdx.x;   // 1024*1536
    int n = idx / 1536, k = idx - n * 1536;
    const float* Wp = (n >> 9) ? Wf : Wi;
    int d = n & 511;
    u16 o;
    if (k < 1024) {
        o = f2bf(Wp[(size_t)(k & 511) * 512 + d]);
    } else {
        float w = Wp[(size_t)(k - 1024) * 512 + d];
        o = f2bf(w - bf2f(f2bf(w)));
    }
    WT[idx] = o;
}

__global__ __launch_bounds__(256) void wconv_kernel(const float* __restrict__ W,
        u16* __restrict__ WT, int lk, int N, int total) {
    int idx = blockIdx.x * 256 + threadIdx.x;
    if (idx >= total) return;
    int n = idx >> lk;
    int k = idx & ((1 << lk) - 1);
    WT[idx] = f2bf(W[(size_t)k * N + n]);
}

// ---------------- concat biases: [q,k,v,o | it,ft] = 3072
__global__ __launch_bounds__(256) void bias_concat_kernel(
        const float* b0, const float* b1, const float* b2,
        const float* b3, const float* b4, const float* b5,
        float* __restrict__ ball) {
    int idx = blockIdx.x * 256 + threadIdx.x;
    if (idx >= 3072) return;
    int p = idx >> 9, d = idx & 511;
    float v;
    switch (p) {
        case 0: v = b0[d]; break;   // bq
        case 1: v = b1[d]; break;   // bk
        case 2: v = b2[d]; break;   // bv
        case 3: v = b3[d]; break;   // bo
        case 4: v = b4[d]; break;   // bi
        default: v = b5[d]; break;  // bf
    }
    ball[idx] = v;
}

// ---------------- LN1: x -> Acorr [16384][1024] = [nH | nL]
__global__ __launch_bounds__(256) void ln1_kernel(const float* __restrict__ x,
        const float* __restrict__ g, const float* __restrict__ bb,
        u16* __restrict__ nout) {
    int wave = threadIdx.x >> 6, lane = threadIdx.x & 63;
    size_t row = (size_t)blockIdx.x * 4 + wave;
    const float* xr = x + row * ND + lane * 8;
    float4 a0 = *(const float4*)xr;
    float4 a1 = *(const float4*)(xr + 4);
    float xs[8] = {a0.x, a0.y, a0.z, a0.w, a1.x, a1.y, a1.z, a1.w};
    float s = 0.f;
#pragma unroll
    for (int u = 0; u < 8; ++u) s += xs[u];
#pragma unroll
    for (int off = 32; off; off >>= 1) s += __shfl_xor(s, off);
    float mu = s * (1.0f / ND);
    float ss = 0.f;
#pragma unroll
    for (int u = 0; u < 8; ++u) { xs[u] -= mu; ss += xs[u] * xs[u]; }
#pragma unroll
    for (int off = 32; off; off >>= 1) ss += __shfl_xor(ss, off);
    float rs = rsqrtf(ss * (1.0f / ND) + 1e-5f);
    const float* gp = g + lane * 8;
    const float* bp = bb + lane * 8;
    float4 g0 = *(const float4*)gp, g1 = *(const float4*)(gp + 4);
    float4 c0 = *(const float4*)bp, c1 = *(const float4*)(bp + 4);
    float gg[8] = {g0.x, g0.y, g0.z, g0.w, g1.x, g1.y, g1.z, g1.w};
    float cc[8] = {c0.x, c0.y, c0.z, c0.w, c1.x, c1.y, c1.z, c1.w};
    u32 owh[4], owl[4];
#pragma unroll
    for (int u = 0; u < 4; ++u) {
        float y0 = xs[2 * u] * rs * gg[2 * u] + cc[2 * u];
        float y1 = xs[2 * u + 1] * rs * gg[2 * u + 1] + cc[2 * u + 1];
        u16 h0 = f2bf(y0), h1 = f2bf(y1);
        u16 l0 = f2bf(y0 - bf2f(h0)), l1 = f2bf(y1 - bf2f(h1));
        owh[u] = (u32)h0 | ((u32)h1 << 16);
        owl[u] = (u32)l0 | ((u32)l1 << 16);
    }
    u16* rb = nout + row * 1024;
    *(uint4*)(rb + lane * 8) = make_uint4(owh[0], owh[1], owh[2], owh[3]);
    *(uint4*)(rb + 512 + lane * 8) = make_uint4(owl[0], owl[1], owl[2], owl[3]);
}

// ---------------- residual add + LN2
__global__ __launch_bounds__(256) void resid_ln2_kernel(const float* __restrict__ x,
        const float* __restrict__ h, const float* __restrict__ g,
        const float* __restrict__ bb, float* __restrict__ outb,
        u16* __restrict__ fin) {
    int wave = threadIdx.x >> 6, lane = threadIdx.x & 63;
    size_t row = (size_t)blockIdx.x * 4 + wave;
    const float* xr = x + row * ND + lane * 8;
    const float* hr = h + row * ND + lane * 8;
    float4 a0 = *(const float4*)xr;
    float4 a1 = *(const float4*)(xr + 4);
    float4 h0 = *(const float4*)hr;
    float4 h1 = *(const float4*)(hr + 4);
    float xs[8] = {a0.x + h0.x, a0.y + h0.y, a0.z + h0.z, a0.w + h0.w,
                   a1.x + h1.x, a1.y + h1.y, a1.z + h1.z, a1.w + h1.w};
    float* orow = outb + row * ND + lane * 8;
    *(float4*)orow = make_float4(xs[0], xs[1], xs[2], xs[3]);
    *(float4*)(orow + 4) = make_float4(xs[4], xs[5], xs[6], xs[7]);
    float s = 0.f;
#pragma unroll
    for (int u = 0; u < 8; ++u) s += xs[u];
#pragma unroll
    for (int off = 32; off; off >>= 1) s += __shfl_xor(s, off);
    float mu = s * (1.0f / ND);
    float ss = 0.f;
#pragma unroll
    for (int u = 0; u < 8; ++u) { xs[u] -= mu; ss += xs[u] * xs[u]; }
#pragma unroll
    for (int off = 32; off; off >>= 1) ss += __shfl_xor(ss, off);
    float rs = rsqrtf(ss * (1.0f / ND) + 1e-5f);
    const float* gp = g + lane * 8;
    const float* bp = bb + lane * 8;
    float4 g0 = *(const float4*)gp, g1 = *(const float4*)(gp + 4);
    float4 c0 = *(const float4*)bp, c1 = *(const float4*)(bp + 4);
    float gg[8] = {g0.x, g0.y, g0.z, g0.w, g1.x, g1.y, g1.z, g1.w};
    float cc[8] = {c0.x, c0.y, c0.z, c0.w, c1.x, c1.y, c1.z, c1.w};
    u32 ow[4];
#pragma unroll
    for (int u = 0; u < 4; ++u) {
        float y0 = xs[2 * u] * rs * gg[2 * u] + cc[2 * u];
        float y1 = xs[2 * u + 1] * rs * gg[2 * u + 1] + cc[2 * u + 1];
        ow[u] = (u32)f2bf(y0) | ((u32)f2bf(y1) << 16);
    }
    *(uint4*)(fin + row * ND + lane * 8) = make_uint4(ow[0], ow[1], ow[2], ow[3]);
}

// ---------------- G kernel: Gm[b,c,t,s] = tril(Q_chunk @ K_chunk^T), bf16
__global__ __launch_bounds__(256) void gqk_kernel(
        const u16* __restrict__ Qb, const u16* __restrict__ Kb,
        u16* __restrict__ Gm) {
    __shared__ u16 Qs[64][520];
    __shared__ u16 Ks[64][520];
    int tid = threadIdx.x;
    int w = tid >> 6, lane = tid & 63;
    int b = blockIdx.x >> 5, c = blockIdx.x & 31;
    int t0 = c * CL;
    {
        int row = tid >> 2, cb = (tid & 3) * 128;
        const u16* qsrc = Qb + ((size_t)b * NS + t0 + row) * ND + cb;
        const u16* ksrc = Kb + ((size_t)b * NS + t0 + row) * ND + cb;
#pragma unroll
        for (int u = 0; u < 16; ++u) {
            *(short8*)&Qs[row][cb + u * 8] = *(const short8*)(qsrc + u * 8);
            *(short8*)&Ks[row][cb + u * 8] = *(const short8*)(ksrc + u * 8);
        }
    }
    __syncthreads();
    int qw = lane & 15, kg = lane >> 4;
    f32x4 ga[4];
#pragma unroll
    for (int ns = 0; ns < 4; ++ns) ga[ns] = (f32x4){0.f, 0.f, 0.f, 0.f};
    for (int kb = 0; kb < 16; ++kb) {
        short8 aq = *(const short8*)&Qs[(w << 4) + qw][kb * 32 + (kg << 3)];
#pragma unroll
        for (int ns = 0; ns < 4; ++ns) {
            short8 bk = *(const short8*)&Ks[(ns << 4) + qw][kb * 32 + (kg << 3)];
            ga[ns] = __builtin_amdgcn_mfma_f32_16x16x32_bf16(aq, bk, ga[ns], 0, 0, 0);
        }
    }
    u16* gout = Gm + (size_t)(b * NCH + c) * CL * CL;
#pragma unroll
    for (int ns = 0; ns < 4; ++ns) {
#pragma unroll
        for (int rg = 0; rg < 4; ++rg) {
            int t = (w << 4) + (kg << 2) + rg;
            int s = (ns << 4) + qw;
            gout[t * CL + s] = (s <= t) ? f2bf(ga[ns][rg]) : (u16)0;
        }
    }
}

// ---------------- chunked mLSTM recurrence, 8 waves (512 thr).
// wg = (batch b, i-slice of 16). Waves: tt = w&3 (t-tile), half = w>>2 (k-split).
// C state: wave w owns j in [w*64, w*64+64) as 4 MFMA accumulators.
__global__ __launch_bounds__(512) void recur_kernel(
        const u16* __restrict__ Qb, const u16* __restrict__ KT,
        const u16* __restrict__ Gm,
        const float* __restrict__ IT, const float* __restrict__ FT,
        const u16* __restrict__ VT, const u16* __restrict__ OT,
        float* __restrict__ H) {
    __shared__ u16 Chi[16][520];
    __shared__ u16 Clo[16][520];
    __shared__ u16 Ub[16][72];
    __shared__ float A1[64][21];
    __shared__ float A2[64][21];
    __shared__ float QCp[4][64][4];
    __shared__ float gam[16];
    __shared__ float mold[16];
    int tid = threadIdx.x;
    int w = tid >> 6, lane = tid & 63;
    int tt = w & 3, half = w >> 2;
    int b = blockIdx.x >> 5;
    int i0 = (blockIdx.x & 31) << 4;
    int qw = lane & 15, kg = lane >> 4;
    if (tid < 16) mold[tid] = 0.f;
    f32x4 cacc[4];
#pragma unroll
    for (int n = 0; n < 4; ++n) cacc[n] = (f32x4){0.f, 0.f, 0.f, 0.f};
    __syncthreads();

    size_t bT = (size_t)b * NS;
    size_t bD = (size_t)b * ND;

    for (int c = 0; c < NCH; ++c) {
        int t0 = c * CL;
        // ---- phase 1: gate scan (2 i's per wave, lane = step)
        for (int r = 0; r < 2; ++r) {
            int il = (w << 1) + r;
            size_t gofs = (bD + i0 + il) * NS + t0 + lane;
            float ft = FT[gofs];
            float it = IT[gofs];
            float vv = bf2f(VT[gofs]);
            float bs = ft;
#pragma unroll
            for (int o = 1; o < 64; o <<= 1) {
                float nv = __shfl_up(bs, o);
                if (lane >= o) bs += nv;
            }
            float e = it - bs;
            float Mv = e;
#pragma unroll
            for (int o = 1; o < 64; o <<= 1) {
                float nv = __shfl_up(Mv, o);
                if (lane >= o) Mv = fmaxf(Mv, nv);
            }
            float mo = mold[il];
            Mv = fmaxf(Mv, mo);
            float E = __shfl(Mv, 63);
            Ub[il][lane] = f2bf(__expf(e - E) * vv);
            A1[lane][il] = __expf(mo - Mv);
            A2[lane][il] = __expf(fminf(E - Mv, 80.f));   // clamp: no inf
            if (lane == 63) {
                gam[il] = __expf(mo - E);
                mold[il] = bs + E;
            }
        }
        // ---- stage C_old (this wave's 64 j-cols) to LDS as bf16 hi/lo
#pragma unroll
        for (int n = 0; n < 4; ++n) {
            int j = (w << 6) + (n << 4) + qw;
#pragma unroll
            for (int rg = 0; rg < 4; ++rg) {
                int irow = (kg << 2) + rg;
                float cv = cacc[n][rg];
                u16 hi = f2bf(cv);
                Chi[irow][j] = hi;
                Clo[irow][j] = f2bf(cv - bf2f(hi));
            }
        }
        __syncthreads();   // Ub/A1/A2/gam/Chi/Clo visible

        // ---- phase 2a: QC partial = Q @ C_old^T over kb half
        f32x4 qch = (f32x4){0.f, 0.f, 0.f, 0.f};
        f32x4 qcl = (f32x4){0.f, 0.f, 0.f, 0.f};
        {
            const u16* qrow = Qb + (bT + t0 + (tt << 4) + qw) * ND + (kg << 3);
            int kb0 = half << 3;
#pragma unroll
            for (int kk = 0; kk < 8; ++kk) {
                int kb = kb0 + kk;
                short8 aq = *(const short8*)(qrow + kb * 32);
                short8 bh = *(const short8*)&Chi[qw][kb * 32 + (kg << 3)];
                short8 bl = *(const short8*)&Clo[qw][kb * 32 + (kg << 3)];
                qch = __builtin_amdgcn_mfma_f32_16x16x32_bf16(aq, bh, qch, 0, 0, 0);
                qcl = __builtin_amdgcn_mfma_f32_16x16x32_bf16(aq, bl, qcl, 0, 0, 0);
            }
        }
        f32x4 qcs;
#pragma unroll
        for (int rg = 0; rg < 4; ++rg) qcs[rg] = qch[rg] + qcl[rg];

        // ---- phase 2b: intra = tril(G) @ U  (half 0 only)
        f32x4 pin = (f32x4){0.f, 0.f, 0.f, 0.f};
        if (half == 0) {
            const u16* grow = Gm + ((size_t)(b * NCH + c) * CL + (tt << 4) + qw) * CL + (kg << 3);
#pragma unroll
            for (int kb = 0; kb < 2; ++kb) {
                short8 ag = *(const short8*)(grow + kb * 32);
                short8 bu = *(const short8*)&Ub[qw][kb * 32 + (kg << 3)];
                pin = __builtin_amdgcn_mfma_f32_16x16x32_bf16(ag, bu, pin, 0, 0, 0);
            }
        }
        // ---- phase 2c: C = gamma*C + U^T @ K  (this wave's 64 j)
        {
            float g[4];
#pragma unroll
            for (int rg = 0; rg < 4; ++rg) g[rg] = gam[(kg << 2) + rg];
#pragma unroll
            for (int n = 0; n < 4; ++n) {
#pragma unroll
                for (int rg = 0; rg < 4; ++rg) cacc[n][rg] *= g[rg];
            }
#pragma unroll
            for (int kb = 0; kb < 2; ++kb) {
                short8 au = *(const short8*)&Ub[qw][kb * 32 + (kg << 3)];
#pragma unroll
                for (int n = 0; n < 4; ++n) {
                    const u16* krow = KT + (bD + (w << 6) + (n << 4) + qw) * NS
                                      + t0 + kb * 32 + (kg << 3);
                    short8 bk = *(const short8*)krow;
                    cacc[n] = __builtin_amdgcn_mfma_f32_16x16x32_bf16(au, bk, cacc[n], 0, 0, 0);
                }
            }
        }
        // ---- reduce QC partials across halves
        if (half == 1) {
            QCp[tt][lane][0] = qcs[0];
            QCp[tt][lane][1] = qcs[1];
            QCp[tt][lane][2] = qcs[2];
            QCp[tt][lane][3] = qcs[3];
        }
        __syncthreads();
        // ---- phase 3: h = o * (A1*QC + A2*intra)  (half 0)
        if (half == 0) {
#pragma unroll
            for (int rg = 0; rg < 4; ++rg) {
                int tl = (tt << 4) + (kg << 2) + rg;
                float qc = qcs[rg] + QCp[tt][lane][rg];
                float o = bf2f(OT[(bD + i0 + qw) * NS + t0 + tl]);
                float h = o * (A1[tl][qw] * qc + A2[tl][qw] * pin[rg]);
                H[(bT + t0 + tl) * ND + i0 + qw] = h;
            }
        }
        __syncthreads();   // A1/A2/Ub/QCp reads done before next chunk overwrites
    }
}

// ---------------- bf16 MFMA GEMM, global_load_lds + XOR swizzle + LDS double-buffer
// MODE 0: qkvo (N=2048) -> QB,KB+KT,VT,OT   MODE 3: itft (N=1024) -> IT,FT
// MODE 1: ffn1 gelu bf16                    MODE 2: ffn2 + resid f32
template <int MODE>
__global__ __launch_bounds__(256) void gemm_kernel(
        const u16* __restrict__ A, const u16* __restrict__ BT,
        int M, int N, int K, int lda, int ldb, int kwrap,
        const float* __restrict__ bias,
        char* __restrict__ pb,
        float* __restrict__ outf, u16* __restrict__ outh,
        const float* __restrict__ resid) {
    __shared__ u16 As[2][128 * 32];
    __shared__ u16 Bs[2][128 * 32];
    int tid = threadIdx.x;
    int wave = tid >> 6, lane = tid & 63;
    int wm = wave >> 1, wn = wave & 1;
    int m0 = blockIdx.y * 128;
    int n0 = blockIdx.x * 128;

    f32x4 acc[4][4];
#pragma unroll
    for (int fi = 0; fi < 4; ++fi)
#pragma unroll
        for (int fj = 0; fj < 4; ++fj)
            acc[fi][fj] = (f32x4){0.f, 0.f, 0.f, 0.f};

    // staging: wave stages rows [wave*32, +32); lane -> (row=l>>2, slot=l&3),
    // global slot pre-swizzled gs = slot ^ ((row>>1)&3)  (LDS stays linear)
    int srow = lane >> 2;
    int slot = lane & 3;
    int r0s = wave * 32 + srow;
    int gs0 = (slot ^ ((r0s >> 1) & 3)) << 3;
    int gs1 = (slot ^ (((r0s + 16) >> 1) & 3)) << 3;
    const u16* Ag0 = A + (size_t)(m0 + r0s) * lda + gs0;
    const u16* Ag1 = A + (size_t)(m0 + r0s + 16) * lda + gs1;
    const u16* Bg0 = BT + (size_t)(n0 + r0s) * ldb + gs0;
    const u16* Bg1 = BT + (size_t)(n0 + r0s + 16) * ldb + gs1;
    int wl0 = wave * 32 * 32;          // wave-uniform LDS elem offsets
    int wl1 = wl0 + 16 * 32;

    int fr = lane & 15, kb = lane >> 4;
    int ra[4], rb4[4], sa[4], sb[4];
#pragma unroll
    for (int f = 0; f < 4; ++f) {
        ra[f] = wm * 64 + f * 16 + fr;
        rb4[f] = wn * 64 + f * 16 + fr;
        sa[f] = ra[f] * 32 + ((kb ^ ((ra[f] >> 1) & 3)) << 3);
        sb[f] = rb4[f] * 32 + ((kb ^ ((rb4[f] >> 1) & 3)) << 3);
    }

    int nk = K >> 5;
    // prologue: stage tile 0 into buffer 0
    __builtin_amdgcn_global_load_lds((gas_u32*)Ag0, (las_u32*)(&As[0][wl0]), 16, 0, 0);
    __builtin_amdgcn_global_load_lds((gas_u32*)Ag1, (las_u32*)(&As[0][wl1]), 16, 0, 0);
    __builtin_amdgcn_global_load_lds((gas_u32*)Bg0, (las_u32*)(&Bs[0][wl0]), 16, 0, 0);
    __builtin_amdgcn_global_load_lds((gas_u32*)Bg1, (las_u32*)(&Bs[0][wl1]), 16, 0, 0);
    __syncthreads();
#pragma unroll 2
    for (int t = 0; t < nk; ++t) {
        int cur = t & 1;
        if (t + 1 < nk) {                     // prefetch tile t+1 into buf^1
            int k0 = (t + 1) << 5;
            int ak0 = k0 - (k0 >= kwrap ? kwrap : 0);
            __builtin_amdgcn_global_load_lds((gas_u32*)(Ag0 + ak0), (las_u32*)(&As[cur ^ 1][wl0]), 16, 0, 0);
            __builtin_amdgcn_global_load_lds((gas_u32*)(Ag1 + ak0), (las_u32*)(&As[cur ^ 1][wl1]), 16, 0, 0);
            __builtin_amdgcn_global_load_lds((gas_u32*)(Bg0 + k0), (las_u32*)(&Bs[cur ^ 1][wl0]), 16, 0, 0);
            __builtin_amdgcn_global_load_lds((gas_u32*)(Bg1 + k0), (las_u32*)(&Bs[cur ^ 1][wl1]), 16, 0, 0);
        }
        short8 fa[4], fb[4];
#pragma unroll
        for (int f = 0; f < 4; ++f) {
            fa[f] = *(const short8*)(&As[cur][sa[f]]);
            fb[f] = *(const short8*)(&Bs[cur][sb[f]]);
        }
#pragma unroll
        for (int fi = 0; fi < 4; ++fi)
#pragma unroll
            for (int fj = 0; fj < 4; ++fj)
                acc[fi][fj] = __builtin_amdgcn_mfma_f32_16x16x32_bf16(
                        fa[fi], fb[fj], acc[fi][fj], 0, 0, 0);
        __syncthreads();   // drains prefetch (vmcnt0) + all reads of buf[cur] done
    }

    int rbase = (lane >> 4) * 4;
    int cbase = n0 + wn * 64 + (lane & 15);
#pragma unroll
    for (int fi = 0; fi < 4; ++fi) {
        int r0 = m0 + wm * 64 + fi * 16 + rbase;
#pragma unroll
        for (int fj = 0; fj < 4; ++fj) {
            int col = cbase + fj * 16;
            if (MODE == 0) {
                int p = col >> 9, d = col & 511;
                float bv_ = bias[col];
                float w0 = acc[fi][fj][0] + bv_;
                float w1 = acc[fi][fj][1] + bv_;
                float w2 = acc[fi][fj][2] + bv_;
                float w3 = acc[fi][fj][3] + bv_;
                size_t tb = ((size_t)(r0 >> 11) * ND + d) * NS + (r0 & 2047);
                if (p == 0) {                  // q
                    u16* q = (u16*)(pb + OFF_QB);
                    q[(size_t)(r0 + 0) * ND + d] = f2bf(w0);
                    q[(size_t)(r0 + 1) * ND + d] = f2bf(w1);
                    q[(size_t)(r0 + 2) * ND + d] = f2bf(w2);
                    q[(size_t)(r0 + 3) * ND + d] = f2bf(w3);
                } else if (p == 1) {           // k scaled: row-major + transposed
                    float s0 = w0 * KSCALE, s1 = w1 * KSCALE;
                    float s2 = w2 * KSCALE, s3 = w3 * KSCALE;
                    u16* kbuf = (u16*)(pb + OFF_KB);
                    kbuf[(size_t)(r0 + 0) * ND + d] = f2bf(s0);
                    kbuf[(size_t)(r0 + 1) * ND + d] = f2bf(s1);
                    kbuf[(size_t)(r0 + 2) * ND + d] = f2bf(s2);
                    kbuf[(size_t)(r0 + 3) * ND + d] = f2bf(s3);
                    uint2 wv = make_uint2((u32)f2bf(s0) | ((u32)f2bf(s1) << 16),
                                          (u32)f2bf(s2) | ((u32)f2bf(s3) << 16));
                    *(uint2*)((u16*)(pb + OFF_KT) + tb) = wv;
                } else if (p == 2) {           // v
                    uint2 wv = make_uint2((u32)f2bf(w0) | ((u32)f2bf(w1) << 16),
                                          (u32)f2bf(w2) | ((u32)f2bf(w3) << 16));
                    *(uint2*)((u16*)(pb + OFF_VT) + tb) = wv;
                } else {                       // o: sigmoid
                    float s0 = 1.0f / (1.0f + __expf(-w0));
                    float s1 = 1.0f / (1.0f + __expf(-w1));
                    float s2 = 1.0f / (1.0f + __expf(-w2));
                    float s3 = 1.0f / (1.0f + __expf(-w3));
                    uint2 wv = make_uint2((u32)f2bf(s0) | ((u32)f2bf(s1) << 16),
                                          (u32)f2bf(s2) | ((u32)f2bf(s3) << 16));
                    *(uint2*)((u16*)(pb + OFF_OT) + tb) = wv;
                }
            } else if (MODE == 3) {
                int p = col >> 9, d = col & 511;
                float bv_ = bias[col];
                float w0 = acc[fi][fj][0] + bv_;
                float w1 = acc[fi][fj][1] + bv_;
                float w2 = acc[fi][fj][2] + bv_;
                float w3 = acc[fi][fj][3] + bv_;
                size_t tb = ((size_t)(r0 >> 11) * ND + d) * NS + (r0 & 2047);
                float* dst = (float*)(pb + (p == 0 ? OFF_IT : OFF_FT));
                *(float4*)(dst + tb) = make_float4(w0, w1, w2, w3);
            } else {
#pragma unroll
                for (int r = 0; r < 4; ++r) {
                    int row = r0 + r;
                    float v = acc[fi][fj][r];
                    if (MODE == 1) {
                        float val = v + bias[col];
                        val = 0.5f * val * (1.0f + erff(val * 0.70710678118654752f));
                        outh[(size_t)row * N + col] = f2bf(val);
                    } else {
                        float val = v + bias[col] + resid[(size_t)row * ND + col];
                        outf[(size_t)row * ND + col] = val;
                    }
                }
            }
        }
    }
}

extern "C" void kernel_launch(void* const* d_in, const int* in_sizes, int n_in,
                              void* d_out, int out_size, void* d_ws, size_t ws_size,
                              hipStream_t stream) {
    const float* x    = (const float*)d_in[0];
    const float* ln1g = (const float*)d_in[1];
    const float* ln1b = (const float*)d_in[2];
    const float* ln2g = (const float*)d_in[3];
    const float* ln2b = (const float*)d_in[4];
    const float* Wq = (const float*)d_in[5];
    const float* bq = (const float*)d_in[6];
    const float* Wk = (const float*)d_in[7];
    const float* bk = (const float*)d_in[8];
    const float* Wv = (const float*)d_in[9];
    const float* bv = (const float*)d_in[10];
    const float* Wi = (const float*)d_in[11];
    const float* bi = (const float*)d_in[12];
    const float* Wf = (const float*)d_in[13];
    const float* bfp = (const float*)d_in[14];
    const float* Wo = (const float*)d_in[15];
    const float* bo = (const float*)d_in[16];
    const float* W1 = (const float*)d_in[17];
    const float* b1 = (const float*)d_in[18];
    const float* W2 = (const float*)d_in[19];
    const float* b2 = (const float*)d_in[20];
    float* out = (float*)d_out;

    char* ws = (char*)d_ws;
    size_t off = 0;
    u16* W4T    = (u16*)(ws + off); off += (size_t)2048 * 512 * 2;   // 2 MB  [q,k,v,o]
    u16* WcT    = (u16*)(ws + off); off += (size_t)1024 * 1536 * 2;  // 3 MB  [it,ft]
    u16* W1T    = (u16*)(ws + off); off += (size_t)2048 * 512 * 2;   // 2 MB
    u16* W2T    = (u16*)(ws + off); off += (size_t)512 * 2048 * 2;   // 2 MB
    float* ball = (float*)(ws + off); off += 3072 * 4;
    off = (off + 255) & ~(size_t)255;
    char* U = ws + off;
    u16*   Acorr = (u16*)(U + OFF_AC);
    float* Hbuf  = (float*)(U + OFF_AC);
    u16* ffnin = (u16*)U;                       // aliases dead Qbf
    u16* Gbuf  = (u16*)(U + OFF_KB);            // aliases dead Kbf/KT/VT/OT
    size_t needed = (size_t)(U - ws) + OFF_AC + (size_t)32 * 1024 * 1024;
    if (ws_size < needed) return;

    // 1. weights
    wconv_kernel<<<1024, 256, 0, stream>>>(Wq, W4T, 9, 512, 512 * 512);
    wconv_kernel<<<1024, 256, 0, stream>>>(Wk, W4T + (size_t)512 * 512, 9, 512, 512 * 512);
    wconv_kernel<<<1024, 256, 0, stream>>>(Wv, W4T + (size_t)2 * 512 * 512, 9, 512, 512 * 512);
    wconv_kernel<<<1024, 256, 0, stream>>>(Wo, W4T + (size_t)3 * 512 * 512, 9, 512, 512 * 512);
    wcorr_kernel<<<(1024 * 1536) / 256, 256, 0, stream>>>(Wi, Wf, WcT);
    wconv_kernel<<<4096, 256, 0, stream>>>(W1, W1T, 9, 2048, 2048 * 512);
    wconv_kernel<<<4096, 256, 0, stream>>>(W2, W2T, 11, 512, 512 * 2048);
    bias_concat_kernel<<<12, 256, 0, stream>>>(bq, bk, bv, bo, bi, bfp, ball);

    // 2. LN1 -> [nH | nL]
    ln1_kernel<<<NM / 4, 256, 0, stream>>>(x, ln1g, ln1b, Acorr);

    // 3a. qkvo GEMM: K=512 (nH @ WH)
    gemm_kernel<0><<<dim3(2048 / 128, NM / 128), 256, 0, stream>>>(
            Acorr, W4T, NM, 2048, 512, 1024, 512, 1 << 30, ball,
            U, nullptr, nullptr, nullptr);
    // 3b. it/ft split-precision GEMM: K=1536, A wraps at 1024
    gemm_kernel<3><<<dim3(1024 / 128, NM / 128), 256, 0, stream>>>(
            Acorr, WcT, NM, 1024, 1536, 1024, 1536, 1024, ball + 2048,
            U, nullptr, nullptr, nullptr);

    // 4a. G = tril(Q K^T) per (batch, chunk)
    gqk_kernel<<<NB * NCH, 256, 0, stream>>>(
            (const u16*)(U + OFF_QB), (const u16*)(U + OFF_KB), (u16*)(U + OFF_G));

    // 4b. chunked recurrence (8 waves, k-split QC)
    recur_kernel<<<NB * 32, 512, 0, stream>>>(
            (const u16*)(U + OFF_QB), (const u16*)(U + OFF_KT), (const u16*)(U + OFF_G),
            (const float*)(U + OFF_IT), (const float*)(U + OFF_FT),
            (const u16*)(U + OFF_VT), (const u16*)(U + OFF_OT), Hbuf);

    // 5. residual + LN2
    resid_ln2_kernel<<<NM / 4, 256, 0, stream>>>(x, Hbuf, ln2g, ln2b, out, ffnin);

    // 6. FFN1
    gemm_kernel<1><<<dim3(2048 / 128, NM / 128), 256, 0, stream>>>(
            ffnin, W1T, NM, 2048, 512, 512, 512, 1 << 30, b1,
            nullptr, nullptr, Gbuf, nullptr);

    // 7. FFN2
    gemm_kernel<2><<<dim3(512 / 128, NM / 128), 256, 0, stream>>>(
            Gbuf, W2T, NM, 512, 2048, 2048, 2048, 1 << 30, b2,
            nullptr, out, nullptr, out);

    (void)in_sizes; (void)n_in; (void)out_size; (void)ws_size;
}